// Round 2
// baseline (352.020 us; speedup 1.0000x reference)
//
#include <hip/hip_runtime.h>
#include <cmath>

#define NB 64
#define NCC 256
#define NH 36
#define NW 36
#define NHW 1296
#define NK 16
#define NI 8
#define SC (1.0f/16.0f)
#define KW 324   // keys per wave in k_attn (1296/4)

__device__ __forceinline__ float hatc(float t){
  t = fminf(fmaxf(t, -1.0f), 1.0f);
  float a = 1.0f + t, bq = 1.0f - t;
  return (t < 0.0f) ? 0.5f*a*a : 1.0f - 0.5f*bq*bq;
}

// ---- K1: PrRoI pooling (weights fused) -> kflat[b][c][16] ---------------
__global__ __launch_bounds__(256) void k_prpool(const float* __restrict__ feat1,
    const float* __restrict__ bb1, float* __restrict__ kflat){
  int bc = blockIdx.x;           // b*256 + c
  int b = bc >> 8;
  int t = threadIdx.x;
  __shared__ float sw[288];      // [0,144)=wY (4 rows of 36), [144,288)=wX
  __shared__ float red[4][16];
  float bx = bb1[b*4+0], by = bb1[b*4+1], bwv = bb1[b*4+2], bhv = bb1[b*4+3];
  float x1 = bx*SC, y1 = by*SC;
  float binw = bwv*SC*0.25f, binh = bhv*SC*0.25f;
  if (t < 144){
    int p = t / 36, i = t - p*36;
    float fi = (float)i;
    float lo = y1 + p*binh, hi = lo + binh;
    sw[t] = hatc(hi - fi) - hatc(lo - fi);
    lo = x1 + p*binw; hi = lo + binw;
    sw[144+t] = hatc(hi - fi) - hatc(lo - fi);
  }
  __syncthreads();
  float acc[16];
  #pragma unroll
  for (int k=0;k<16;k++) acc[k]=0.0f;
  const float* fp = feat1 + (size_t)bc*NHW;
  for (int idx=t; idx<NHW; idx+=256){
    int h = idx/36;
    int w = idx - h*36;
    float v = fp[idx];
    float v0 = v*sw[h], v1 = v*sw[36+h], v2 = v*sw[72+h], v3 = v*sw[108+h];
    float wx0 = sw[144+w], wx1 = sw[180+w], wx2 = sw[216+w], wx3 = sw[252+w];
    acc[0] += v0*wx0;  acc[1] += v0*wx1;  acc[2] += v0*wx2;  acc[3] += v0*wx3;
    acc[4] += v1*wx0;  acc[5] += v1*wx1;  acc[6] += v1*wx2;  acc[7] += v1*wx3;
    acc[8] += v2*wx0;  acc[9] += v2*wx1;  acc[10]+= v2*wx2;  acc[11]+= v2*wx3;
    acc[12]+= v3*wx0;  acc[13]+= v3*wx1;  acc[14]+= v3*wx2;  acc[15]+= v3*wx3;
  }
  #pragma unroll
  for (int k=0;k<16;k++){
    float a = acc[k];
    #pragma unroll
    for (int off=32; off>0; off>>=1) a += __shfl_down(a, off);
    acc[k] = a;
  }
  int wv = t >> 6;
  if ((t & 63) == 0){
    #pragma unroll
    for (int k=0;k<16;k++) red[wv][k] = acc[k];
  }
  __syncthreads();
  if (t < 16){
    float area = binw*binh;
    float ia = (area > 0.0f) ? 1.0f/fmaxf(area,1e-12f) : 0.0f;
    float s = red[0][t] + red[1][t] + red[2][t] + red[3][t];
    kflat[(size_t)bc*16 + t] = s * ia;
  }
}

// ---- K2: pixel correlation corr[b][k][hw] + per-block channel sums ------
__global__ __launch_bounds__(256) void k_corr(const float* __restrict__ feat2,
    const float* __restrict__ kflat, float* __restrict__ corr,
    float* __restrict__ partial){
  int blk = blockIdx.x;
  int b = blk / 6;
  int ch = blk - b*6;
  int t = threadIdx.x;
  __shared__ float kl[4096];
  __shared__ float red[4][16];
  for (int i=t; i<4096; i+=256) kl[i] = kflat[(size_t)b*4096 + i];
  __syncthreads();
  int pix = ch*256 + t;
  bool act = pix < NHW;
  float acc[16];
  #pragma unroll
  for (int k=0;k<16;k++) acc[k]=0.0f;
  if (act){
    const float* f2 = feat2 + (size_t)b*NCC*NHW + pix;
    for (int c=0;c<NCC;c++){
      float v = f2[(size_t)c*NHW];
      const float4* k4 = (const float4*)(&kl[c*16]);
      float4 ka = k4[0], kb = k4[1], kc = k4[2], kd = k4[3];
      acc[0]+=v*ka.x; acc[1]+=v*ka.y; acc[2]+=v*ka.z; acc[3]+=v*ka.w;
      acc[4]+=v*kb.x; acc[5]+=v*kb.y; acc[6]+=v*kb.z; acc[7]+=v*kb.w;
      acc[8]+=v*kc.x; acc[9]+=v*kc.y; acc[10]+=v*kc.z; acc[11]+=v*kc.w;
      acc[12]+=v*kd.x; acc[13]+=v*kd.y; acc[14]+=v*kd.z; acc[15]+=v*kd.w;
    }
    float* cp = corr + (size_t)b*NK*NHW + pix;
    #pragma unroll
    for (int k=0;k<16;k++) cp[(size_t)k*NHW] = acc[k];
  }
  #pragma unroll
  for (int k=0;k<16;k++){
    float a = acc[k];
    #pragma unroll
    for (int off=32; off>0; off>>=1) a += __shfl_down(a, off);
    acc[k] = a;
  }
  int wv = t >> 6;
  if ((t & 63)==0){
    #pragma unroll
    for (int k=0;k<16;k++) red[wv][k]=acc[k];
  }
  __syncthreads();
  if (t < 16)
    partial[(size_t)blk*16 + t] = red[0][t]+red[1][t]+red[2][t]+red[3][t];
}

// ---- K3: SE gate (fused) + theta/phi/g projections ----------------------
__global__ __launch_bounds__(256) void k_tpg(const float* __restrict__ corr,
    const float* __restrict__ partial,
    const float* __restrict__ w1, const float* __restrict__ w2,
    const float* __restrict__ tw, const float* __restrict__ tb,
    const float* __restrict__ pw, const float* __restrict__ pb,
    const float* __restrict__ gw, const float* __restrict__ gb,
    float* __restrict__ sscale,
    float* __restrict__ theta, float* __restrict__ phi, float* __restrict__ g){
  int blk = blockIdx.x;
  int b = blk/6;
  int ch = blk - b*6;
  int t = threadIdx.x;
  __shared__ float Wt[128], Wp[128], Wg[128], Bz[24], Ss[16], sS[16], sR[4];
  if (t < 128){ Wt[t]=tw[t]; Wp[t]=pw[t]; Wg[t]=gw[t]; }
  if (t < 8){ Bz[t]=tb[t]; Bz[8+t]=pb[t]; Bz[16+t]=gb[t]; }
  // SE gate computed per-block from partials (cheap, removes a kernel)
  if (t < 16){
    float a = 0.f;
    #pragma unroll
    for (int c2=0; c2<6; c2++) a += partial[(b*6+c2)*16 + t];
    sS[t] = a * (1.0f/1296.0f);
  }
  __syncthreads();
  if (t < 4){
    float a=0.f;
    #pragma unroll
    for (int k=0;k<16;k++) a += sS[k]*w1[t*16+k];
    sR[t] = fmaxf(a, 0.f);
  }
  __syncthreads();
  if (t < 16){
    float a=0.f;
    #pragma unroll
    for (int j=0;j<4;j++) a += sR[j]*w2[t*4+j];
    float gsc = 1.0f/(1.0f+__expf(-a));
    Ss[t] = gsc;
    if (ch == 0) sscale[b*16+t] = gsc;
  }
  __syncthreads();
  int n = ch*256 + t;
  if (n >= NHW) return;
  float x[16];
  const float* cp = corr + (size_t)b*NK*NHW + n;
  #pragma unroll
  for (int c=0;c<16;c++) x[c] = cp[(size_t)c*NHW] * Ss[c];
  float th[8], ph[8], gg[8];
  #pragma unroll
  for (int o=0;o<8;o++){
    float a=Bz[o], p2=Bz[8+o], gq=Bz[16+o];
    #pragma unroll
    for (int c=0;c<16;c++){
      a  += Wt[o*16+c]*x[c];
      p2 += Wp[o*16+c]*x[c];
      gq += Wg[o*16+c]*x[c];
    }
    th[o]=a; ph[o]=p2; gg[o]=gq;
  }
  size_t base = ((size_t)b*NHW + n)*8;
  #pragma unroll
  for (int o=0;o<8;o++){ theta[base+o]=th[o]; phi[base+o]=ph[o]; g[base+o]=gg[o]; }
}

// ---- K4: flash attention, 4 waves split keys, LDS tree-merge ------------
__global__ __launch_bounds__(256) void k_attn(const float* __restrict__ theta,
    const float* __restrict__ phi, const float* __restrict__ g,
    const float* __restrict__ corr, const float* __restrict__ sscale,
    const float* __restrict__ Ww, const float* __restrict__ Wb,
    float* __restrict__ out){
  int blk = blockIdx.x;
  int b = blk / 21;
  int ch = blk - b*21;
  int t = threadIdx.x;
  int w = t >> 6;
  int lane = t & 63;
  int n = ch*64 + lane;
  bool act = n < NHW;
  __shared__ float sdat[2][64][13];   // m, l, y[8] (stride 13: conflict-free)
  __shared__ float syf[8][64];

  float th[8];
  {
    const float4* tp = (const float4*)(theta + ((size_t)b*NHW + (act ? n : 0))*8);
    float4 a0 = tp[0], a1 = tp[1];
    th[0]=a0.x; th[1]=a0.y; th[2]=a0.z; th[3]=a0.w;
    th[4]=a1.x; th[5]=a1.y; th[6]=a1.z; th[7]=a1.w;
  }
  float mr = -INFINITY, l = 0.0f;
  float y[8] = {0,0,0,0,0,0,0,0};
  const float* pb2 = phi + (size_t)b*NHW*8;
  const float* gb2 = g   + (size_t)b*NHW*8;

  if (act){
    for (int j = w*KW; j < (w+1)*KW; j += 4){
      float s[4];
      #pragma unroll
      for (int u=0; u<4; u++){
        const float4* pr = (const float4*)(pb2 + (size_t)(j+u)*8);
        float4 p0 = pr[0], p1 = pr[1];
        s[u] = th[0]*p0.x + th[1]*p0.y + th[2]*p0.z + th[3]*p0.w
             + th[4]*p1.x + th[5]*p1.y + th[6]*p1.z + th[7]*p1.w;
      }
      float cm = fmaxf(fmaxf(s[0],s[1]), fmaxf(s[2],s[3]));
      if (cm > mr){
        float cf = __expf(mr - cm);
        mr = cm;
        l *= cf;
        #pragma unroll
        for (int o=0;o<8;o++) y[o] *= cf;
      }
      #pragma unroll
      for (int u=0; u<4; u++){
        float p = __expf(s[u] - mr);
        l += p;
        const float4* gr = (const float4*)(gb2 + (size_t)(j+u)*8);
        float4 g0 = gr[0], g1 = gr[1];
        y[0]+=p*g0.x; y[1]+=p*g0.y; y[2]+=p*g0.z; y[3]+=p*g0.w;
        y[4]+=p*g1.x; y[5]+=p*g1.y; y[6]+=p*g1.z; y[7]+=p*g1.w;
      }
    }
  }

  // tree-merge partials: waves {2,3} -> {0,1} -> 0
  if (w >= 2){
    float* d = sdat[w-2][lane];
    d[0]=mr; d[1]=l;
    #pragma unroll
    for (int o=0;o<8;o++) d[2+o]=y[o];
  }
  __syncthreads();
  if (w < 2){
    const float* d = sdat[w][lane];
    float m2=d[0], l2=d[1];
    float mm = fmaxf(mr, m2);
    float c1 = __expf(mr-mm), c2 = __expf(m2-mm);
    mr = mm; l = l*c1 + l2*c2;
    #pragma unroll
    for (int o=0;o<8;o++) y[o] = y[o]*c1 + d[2+o]*c2;
  }
  __syncthreads();
  if (w == 1){
    float* d = sdat[0][lane];
    d[0]=mr; d[1]=l;
    #pragma unroll
    for (int o=0;o<8;o++) d[2+o]=y[o];
  }
  __syncthreads();
  if (w == 0){
    const float* d = sdat[0][lane];
    float m2=d[0], l2=d[1];
    float mm = fmaxf(mr, m2);
    float c1 = __expf(mr-mm), c2 = __expf(m2-mm);
    l = l*c1 + l2*c2;
    float invl = 1.0f / l;
    #pragma unroll
    for (int o=0;o<8;o++) syf[o][lane] = (y[o]*c1 + d[2+o]*c2)*invl;
  }
  __syncthreads();

  // epilogue: each wave handles 4 output channels
  if (act){
    float yv[8];
    #pragma unroll
    for (int o=0;o<8;o++) yv[o] = syf[o][lane];
    const float* cp = corr + (size_t)b*NK*NHW + n;
    const float* ss = sscale + b*16;
    float* op = out + (size_t)b*NK*NHW + n;
    #pragma unroll
    for (int q=0;q<4;q++){
      int c2 = w*4+q;
      float z = Wb[c2];
      #pragma unroll
      for (int o=0;o<8;o++) z += Ww[c2*8+o]*yv[o];
      op[(size_t)c2*NHW] = z + cp[(size_t)c2*NHW]*ss[c2];
    }
  }
}

extern "C" void kernel_launch(void* const* d_in, const int* in_sizes, int n_in,
                              void* d_out, int out_size, void* d_ws, size_t ws_size,
                              hipStream_t stream){
  const float* feat1 = (const float*)d_in[0];
  const float* feat2 = (const float*)d_in[1];
  const float* bb1   = (const float*)d_in[2];
  const float* se_w1 = (const float*)d_in[3];
  const float* se_w2 = (const float*)d_in[4];
  const float* tw    = (const float*)d_in[5];
  const float* tb    = (const float*)d_in[6];
  const float* pw    = (const float*)d_in[7];
  const float* pb    = (const float*)d_in[8];
  const float* gw    = (const float*)d_in[9];
  const float* gb    = (const float*)d_in[10];
  const float* Ww    = (const float*)d_in[11];
  const float* Wb    = (const float*)d_in[12];
  float* out = (float*)d_out;

  float* ws = (float*)d_ws;
  float* kflat    = ws;                              // 64*256*16
  float* corr     = kflat + 64*256*16;               // 64*16*1296
  float* partial  = corr + (size_t)64*16*1296;       // 64*6*16
  float* sscale   = partial + 64*6*16;               // 64*16
  float* theta    = sscale + 64*16;                  // 64*1296*8
  float* phi      = theta + (size_t)64*1296*8;       // 64*1296*8
  float* g        = phi   + (size_t)64*1296*8;       // 64*1296*8

  hipLaunchKernelGGL(k_prpool, dim3(64*256), dim3(256), 0, stream, feat1, bb1, kflat);
  hipLaunchKernelGGL(k_corr, dim3(64*6), dim3(256), 0, stream, feat2, kflat, corr, partial);
  hipLaunchKernelGGL(k_tpg, dim3(64*6), dim3(256), 0, stream, corr, partial,
                     se_w1, se_w2, tw, tb, pw, pb, gw, gb, sscale, theta, phi, g);
  hipLaunchKernelGGL(k_attn, dim3(64*21), dim3(256), 0, stream, theta, phi, g, corr, sscale, Ww, Wb, out);
}

// Round 3
// 233.871 us; speedup vs baseline: 1.5052x; 1.5052x over previous
//
#include <hip/hip_runtime.h>
#include <cmath>

#define NB 64
#define NCC 256
#define NH 36
#define NW 36
#define NHW 1296
#define NK 16
#define NI 8
#define SC (1.0f/16.0f)
#define KW 324   // keys per wave in k_attn (1296/4)
#define LOG2E 1.4426950408889634f

typedef __attribute__((ext_vector_type(16))) float f32x16;

__device__ __forceinline__ float hatc(float t){
  t = fminf(fmaxf(t, -1.0f), 1.0f);
  float a = 1.0f + t, bq = 1.0f - t;
  return (t < 0.0f) ? 0.5f*a*a : 1.0f - 0.5f*bq*bq;
}

// ---- K1: PrRoI pooling (weights fused) -> kflat[b][c][16] ---------------
__global__ __launch_bounds__(256) void k_prpool(const float* __restrict__ feat1,
    const float* __restrict__ bb1, float* __restrict__ kflat){
  int bc = blockIdx.x;           // b*256 + c
  int b = bc >> 8;
  int t = threadIdx.x;
  __shared__ float sw[288];      // [0,144)=wY (4 rows of 36), [144,288)=wX
  __shared__ float red[4][16];
  float bx = bb1[b*4+0], by = bb1[b*4+1], bwv = bb1[b*4+2], bhv = bb1[b*4+3];
  float x1 = bx*SC, y1 = by*SC;
  float binw = bwv*SC*0.25f, binh = bhv*SC*0.25f;
  if (t < 144){
    int p = t / 36, i = t - p*36;
    float fi = (float)i;
    float lo = y1 + p*binh, hi = lo + binh;
    sw[t] = hatc(hi - fi) - hatc(lo - fi);
    lo = x1 + p*binw; hi = lo + binw;
    sw[144+t] = hatc(hi - fi) - hatc(lo - fi);
  }
  __syncthreads();
  float acc[16];
  #pragma unroll
  for (int k=0;k<16;k++) acc[k]=0.0f;
  const float* fp = feat1 + (size_t)bc*NHW;
  for (int idx=t; idx<NHW; idx+=256){
    int h = idx/36;
    int w = idx - h*36;
    float v = fp[idx];
    float v0 = v*sw[h], v1 = v*sw[36+h], v2 = v*sw[72+h], v3 = v*sw[108+h];
    float wx0 = sw[144+w], wx1 = sw[180+w], wx2 = sw[216+w], wx3 = sw[252+w];
    acc[0] += v0*wx0;  acc[1] += v0*wx1;  acc[2] += v0*wx2;  acc[3] += v0*wx3;
    acc[4] += v1*wx0;  acc[5] += v1*wx1;  acc[6] += v1*wx2;  acc[7] += v1*wx3;
    acc[8] += v2*wx0;  acc[9] += v2*wx1;  acc[10]+= v2*wx2;  acc[11]+= v2*wx3;
    acc[12]+= v3*wx0;  acc[13]+= v3*wx1;  acc[14]+= v3*wx2;  acc[15]+= v3*wx3;
  }
  #pragma unroll
  for (int k=0;k<16;k++){
    float a = acc[k];
    #pragma unroll
    for (int off=32; off>0; off>>=1) a += __shfl_down(a, off);
    acc[k] = a;
  }
  int wv = t >> 6;
  if ((t & 63) == 0){
    #pragma unroll
    for (int k=0;k<16;k++) red[wv][k] = acc[k];
  }
  __syncthreads();
  if (t < 16){
    float area = binw*binh;
    float ia = (area > 0.0f) ? 1.0f/fmaxf(area,1e-12f) : 0.0f;
    float s = red[0][t] + red[1][t] + red[2][t] + red[3][t];
    kflat[(size_t)bc*16 + t] = s * ia;
  }
}

// ---- K2: pixel correlation corr[b][k][hw] + per-block channel sums ------
__global__ __launch_bounds__(256) void k_corr(const float* __restrict__ feat2,
    const float* __restrict__ kflat, float* __restrict__ corr,
    float* __restrict__ partial){
  int blk = blockIdx.x;
  int b = blk / 6;
  int ch = blk - b*6;
  int t = threadIdx.x;
  __shared__ float kl[4096];
  __shared__ float red[4][16];
  for (int i=t; i<4096; i+=256) kl[i] = kflat[(size_t)b*4096 + i];
  __syncthreads();
  int pix = ch*256 + t;
  bool act = pix < NHW;
  float acc[16];
  #pragma unroll
  for (int k=0;k<16;k++) acc[k]=0.0f;
  if (act){
    const float* f2 = feat2 + (size_t)b*NCC*NHW + pix;
    for (int c=0;c<NCC;c++){
      float v = f2[(size_t)c*NHW];
      const float4* k4 = (const float4*)(&kl[c*16]);
      float4 ka = k4[0], kb = k4[1], kc = k4[2], kd = k4[3];
      acc[0]+=v*ka.x; acc[1]+=v*ka.y; acc[2]+=v*ka.z; acc[3]+=v*ka.w;
      acc[4]+=v*kb.x; acc[5]+=v*kb.y; acc[6]+=v*kb.z; acc[7]+=v*kb.w;
      acc[8]+=v*kc.x; acc[9]+=v*kc.y; acc[10]+=v*kc.z; acc[11]+=v*kc.w;
      acc[12]+=v*kd.x; acc[13]+=v*kd.y; acc[14]+=v*kd.z; acc[15]+=v*kd.w;
    }
    float* cp = corr + (size_t)b*NK*NHW + pix;
    #pragma unroll
    for (int k=0;k<16;k++) cp[(size_t)k*NHW] = acc[k];
  }
  #pragma unroll
  for (int k=0;k<16;k++){
    float a = acc[k];
    #pragma unroll
    for (int off=32; off>0; off>>=1) a += __shfl_down(a, off);
    acc[k] = a;
  }
  int wv = t >> 6;
  if ((t & 63)==0){
    #pragma unroll
    for (int k=0;k<16;k++) red[wv][k]=acc[k];
  }
  __syncthreads();
  if (t < 16)
    partial[(size_t)blk*16 + t] = red[0][t]+red[1][t]+red[2][t]+red[3][t];
}

// ---- K3: SE gate (fused) + theta / interleaved {phi,g} projections ------
__global__ __launch_bounds__(256) void k_tpg(const float* __restrict__ corr,
    const float* __restrict__ partial,
    const float* __restrict__ w1, const float* __restrict__ w2,
    const float* __restrict__ tw, const float* __restrict__ tb,
    const float* __restrict__ pw, const float* __restrict__ pb,
    const float* __restrict__ gw, const float* __restrict__ gb,
    float* __restrict__ sscale,
    float* __restrict__ theta, float* __restrict__ pg){
  int blk = blockIdx.x;
  int b = blk/6;
  int ch = blk - b*6;
  int t = threadIdx.x;
  __shared__ float Wt[128], Wp[128], Wg[128], Bz[24], Ss[16], sS[16], sR[4];
  if (t < 128){ Wt[t]=tw[t]; Wp[t]=pw[t]; Wg[t]=gw[t]; }
  if (t < 8){ Bz[t]=tb[t]; Bz[8+t]=pb[t]; Bz[16+t]=gb[t]; }
  if (t < 16){
    float a = 0.f;
    #pragma unroll
    for (int c2=0; c2<6; c2++) a += partial[(b*6+c2)*16 + t];
    sS[t] = a * (1.0f/1296.0f);
  }
  __syncthreads();
  if (t < 4){
    float a=0.f;
    #pragma unroll
    for (int k=0;k<16;k++) a += sS[k]*w1[t*16+k];
    sR[t] = fmaxf(a, 0.f);
  }
  __syncthreads();
  if (t < 16){
    float a=0.f;
    #pragma unroll
    for (int j=0;j<4;j++) a += sR[j]*w2[t*4+j];
    float gsc = 1.0f/(1.0f+__expf(-a));
    Ss[t] = gsc;
    if (ch == 0) sscale[b*16+t] = gsc;
  }
  __syncthreads();
  int n = ch*256 + t;
  if (n >= NHW) return;
  float x[16];
  const float* cp = corr + (size_t)b*NK*NHW + n;
  #pragma unroll
  for (int c=0;c<16;c++) x[c] = cp[(size_t)c*NHW] * Ss[c];
  float th[8], ph[8], gg[8];
  #pragma unroll
  for (int o=0;o<8;o++){
    float a=Bz[o], p2=Bz[8+o], gq=Bz[16+o];
    #pragma unroll
    for (int c=0;c<16;c++){
      a  += Wt[o*16+c]*x[c];
      p2 += Wp[o*16+c]*x[c];
      gq += Wg[o*16+c]*x[c];
    }
    th[o]=a; ph[o]=p2; gg[o]=gq;
  }
  {
    size_t tbase = ((size_t)b*NHW + n)*8;
    float4* tp = (float4*)(theta + tbase);
    tp[0] = make_float4(th[0],th[1],th[2],th[3]);
    tp[1] = make_float4(th[4],th[5],th[6],th[7]);
  }
  {
    size_t base = ((size_t)b*NHW + n)*16;
    float4* pp = (float4*)(pg + base);
    pp[0] = make_float4(ph[0],ph[1],ph[2],ph[3]);
    pp[1] = make_float4(ph[4],ph[5],ph[6],ph[7]);
    pp[2] = make_float4(gg[0],gg[1],gg[2],gg[3]);
    pp[3] = make_float4(gg[4],gg[5],gg[6],gg[7]);
  }
}

// ---- K4: flash attention; phi/g via SCALAR loads (wave-uniform rows) ----
__global__ __launch_bounds__(256) void k_attn(const float* __restrict__ theta,
    const float* __restrict__ pg,
    const float* __restrict__ corr, const float* __restrict__ sscale,
    const float* __restrict__ Ww, const float* __restrict__ Wb,
    float* __restrict__ out){
  int blk = blockIdx.x;
  int b = blk / 21;
  int ch = blk - b*21;
  int t = threadIdx.x;
  int w = t >> 6;
  int lane = t & 63;
  int n = ch*64 + lane;
  bool act = n < NHW;
  __shared__ float sdat[2][64][13];
  __shared__ float syf[8][64];

  float th[8];
  {
    const float4* tp = (const float4*)(theta + ((size_t)b*NHW + (act ? n : 0))*8);
    float4 a0 = tp[0], a1 = tp[1];
    // pre-scale by log2(e): do softmax entirely in exp2 domain
    th[0]=a0.x*LOG2E; th[1]=a0.y*LOG2E; th[2]=a0.z*LOG2E; th[3]=a0.w*LOG2E;
    th[4]=a1.x*LOG2E; th[5]=a1.y*LOG2E; th[6]=a1.z*LOG2E; th[7]=a1.w*LOG2E;
  }
  float mr = -1e30f, l = 0.0f;
  float y[8] = {0,0,0,0,0,0,0,0};

  // wave-uniform key range -> scalar (SGPR) loads of pg rows
  int wu = __builtin_amdgcn_readfirstlane(w);
  const f32x16* pgb = (const f32x16*)(pg + (size_t)b*NHW*16);

  if (act){
    for (int j = wu*KW; j < (wu+1)*KW; j += 4){
      f32x16 r0 = pgb[j+0];
      f32x16 r1 = pgb[j+1];
      f32x16 r2 = pgb[j+2];
      f32x16 r3 = pgb[j+3];
      float s0 = th[0]*r0[0]+th[1]*r0[1]+th[2]*r0[2]+th[3]*r0[3]
               + th[4]*r0[4]+th[5]*r0[5]+th[6]*r0[6]+th[7]*r0[7];
      float s1 = th[0]*r1[0]+th[1]*r1[1]+th[2]*r1[2]+th[3]*r1[3]
               + th[4]*r1[4]+th[5]*r1[5]+th[6]*r1[6]+th[7]*r1[7];
      float s2 = th[0]*r2[0]+th[1]*r2[1]+th[2]*r2[2]+th[3]*r2[3]
               + th[4]*r2[4]+th[5]*r2[5]+th[6]*r2[6]+th[7]*r2[7];
      float s3 = th[0]*r3[0]+th[1]*r3[1]+th[2]*r3[2]+th[3]*r3[3]
               + th[4]*r3[4]+th[5]*r3[5]+th[6]*r3[6]+th[7]*r3[7];
      float cm = fmaxf(fmaxf(s0,s1), fmaxf(s2,s3));
      float mn = fmaxf(mr, cm);
      float cf = __builtin_amdgcn_exp2f(mr - mn);   // ==0 first iter, ==1 if no new max
      mr = mn;
      float p0 = __builtin_amdgcn_exp2f(s0 - mn);
      float p1 = __builtin_amdgcn_exp2f(s1 - mn);
      float p2 = __builtin_amdgcn_exp2f(s2 - mn);
      float p3 = __builtin_amdgcn_exp2f(s3 - mn);
      l = l*cf + ((p0+p1) + (p2+p3));
      #pragma unroll
      for (int o=0;o<8;o++)
        y[o] = y[o]*cf + (p0*r0[8+o] + p1*r1[8+o]) + (p2*r2[8+o] + p3*r3[8+o]);
    }
  }

  // tree-merge partials: waves {2,3} -> {0,1} -> 0   (all in exp2 domain)
  if (w >= 2){
    float* d = sdat[w-2][lane];
    d[0]=mr; d[1]=l;
    #pragma unroll
    for (int o=0;o<8;o++) d[2+o]=y[o];
  }
  __syncthreads();
  if (w < 2){
    const float* d = sdat[w][lane];
    float m2=d[0], l2=d[1];
    float mm = fmaxf(mr, m2);
    float c1 = __builtin_amdgcn_exp2f(mr-mm), c2 = __builtin_amdgcn_exp2f(m2-mm);
    mr = mm; l = l*c1 + l2*c2;
    #pragma unroll
    for (int o=0;o<8;o++) y[o] = y[o]*c1 + d[2+o]*c2;
  }
  __syncthreads();
  if (w == 1){
    float* d = sdat[0][lane];
    d[0]=mr; d[1]=l;
    #pragma unroll
    for (int o=0;o<8;o++) d[2+o]=y[o];
  }
  __syncthreads();
  if (w == 0){
    const float* d = sdat[0][lane];
    float m2=d[0], l2=d[1];
    float mm = fmaxf(mr, m2);
    float c1 = __builtin_amdgcn_exp2f(mr-mm), c2 = __builtin_amdgcn_exp2f(m2-mm);
    l = l*c1 + l2*c2;
    float invl = 1.0f / l;
    #pragma unroll
    for (int o=0;o<8;o++) syf[o][lane] = (y[o]*c1 + d[2+o]*c2)*invl;
  }
  __syncthreads();

  // epilogue: each wave handles 4 output channels
  if (act){
    float yv[8];
    #pragma unroll
    for (int o=0;o<8;o++) yv[o] = syf[o][lane];
    const float* cp = corr + (size_t)b*NK*NHW + n;
    const float* ss = sscale + b*16;
    float* op = out + (size_t)b*NK*NHW + n;
    #pragma unroll
    for (int q=0;q<4;q++){
      int c2 = w*4+q;
      float z = Wb[c2];
      #pragma unroll
      for (int o=0;o<8;o++) z += Ww[c2*8+o]*yv[o];
      op[(size_t)c2*NHW] = z + cp[(size_t)c2*NHW]*ss[c2];
    }
  }
}

extern "C" void kernel_launch(void* const* d_in, const int* in_sizes, int n_in,
                              void* d_out, int out_size, void* d_ws, size_t ws_size,
                              hipStream_t stream){
  const float* feat1 = (const float*)d_in[0];
  const float* feat2 = (const float*)d_in[1];
  const float* bb1   = (const float*)d_in[2];
  const float* se_w1 = (const float*)d_in[3];
  const float* se_w2 = (const float*)d_in[4];
  const float* tw    = (const float*)d_in[5];
  const float* tb    = (const float*)d_in[6];
  const float* pw    = (const float*)d_in[7];
  const float* pb    = (const float*)d_in[8];
  const float* gw    = (const float*)d_in[9];
  const float* gb    = (const float*)d_in[10];
  const float* Ww    = (const float*)d_in[11];
  const float* Wb    = (const float*)d_in[12];
  float* out = (float*)d_out;

  float* ws = (float*)d_ws;
  float* kflat    = ws;                              // 64*256*16
  float* corr     = kflat + 64*256*16;               // 64*16*1296
  float* partial  = corr + (size_t)64*16*1296;       // 64*6*16
  float* sscale   = partial + 64*6*16;               // 64*16
  float* theta    = sscale + 64*16;                  // 64*1296*8
  float* pg       = theta + (size_t)64*1296*8;       // 64*1296*16 interleaved {phi,g}

  hipLaunchKernelGGL(k_prpool, dim3(64*256), dim3(256), 0, stream, feat1, bb1, kflat);
  hipLaunchKernelGGL(k_corr, dim3(64*6), dim3(256), 0, stream, feat2, kflat, corr, partial);
  hipLaunchKernelGGL(k_tpg, dim3(64*6), dim3(256), 0, stream, corr, partial,
                     se_w1, se_w2, tw, tb, pw, pb, gw, gb, sscale, theta, pg);
  hipLaunchKernelGGL(k_attn, dim3(64*21), dim3(256), 0, stream, theta, pg, corr, sscale, Ww, Wb, out);
}

// Round 4
// 163.244 us; speedup vs baseline: 2.1564x; 1.4327x over previous
//
#include <hip/hip_runtime.h>
#include <cmath>

#define NB 64
#define NCC 256
#define NH 36
#define NW 36
#define NHW 1296
#define NK 16
#define NI 8
#define SC (1.0f/16.0f)
#define LOG2E 1.4426950408889634f

typedef __attribute__((ext_vector_type(16))) float f32x16;
typedef __attribute__((ext_vector_type(2)))  float f32x2;

__device__ __forceinline__ float hatc(float t){
  t = fminf(fmaxf(t, -1.0f), 1.0f);
  float a = 1.0f + t, bq = 1.0f - t;
  return (t < 0.0f) ? 0.5f*a*a : 1.0f - 0.5f*bq*bq;
}

// ---- K1: PrRoI pooling; 1 wave per (b,c), 4 channels per block ----------
__global__ __launch_bounds__(256) void k_prpool(const float* __restrict__ feat1,
    const float* __restrict__ bb1, float* __restrict__ kflat){
  int blk = blockIdx.x;          // b*64 + cg
  int b = blk >> 6, cg = blk & 63;
  int t = threadIdx.x, w = t >> 6, lane = t & 63;
  int c = cg*4 + w;
  __shared__ float sw[288];      // [0,144)=wY (4 rows of 36), [144,288)=wX
  float bx = bb1[b*4+0], by = bb1[b*4+1], bwv = bb1[b*4+2], bhv = bb1[b*4+3];
  float x1 = bx*SC, y1 = by*SC;
  float binw = bwv*SC*0.25f, binh = bhv*SC*0.25f;
  if (t < 144){
    int p = t / 36, i = t - p*36;
    float fi = (float)i;
    float lo = y1 + p*binh, hi = lo + binh;
    sw[t] = hatc(hi - fi) - hatc(lo - fi);
    lo = x1 + p*binw; hi = lo + binw;
    sw[144+t] = hatc(hi - fi) - hatc(lo - fi);
  }
  __syncthreads();
  float acc[16];
  #pragma unroll
  for (int k=0;k<16;k++) acc[k]=0.0f;
  const float* fp = feat1 + ((size_t)(b*256+c))*NHW;
  #pragma unroll 4
  for (int i=0;i<20;i++){
    int idx = i*64 + lane;
    int h = idx/36, ww = idx - h*36;
    float v = fp[idx];
    float v0 = v*sw[h], v1 = v*sw[36+h], v2 = v*sw[72+h], v3 = v*sw[108+h];
    float wx0 = sw[144+ww], wx1 = sw[180+ww], wx2 = sw[216+ww], wx3 = sw[252+ww];
    acc[0] += v0*wx0;  acc[1] += v0*wx1;  acc[2] += v0*wx2;  acc[3] += v0*wx3;
    acc[4] += v1*wx0;  acc[5] += v1*wx1;  acc[6] += v1*wx2;  acc[7] += v1*wx3;
    acc[8] += v2*wx0;  acc[9] += v2*wx1;  acc[10]+= v2*wx2;  acc[11]+= v2*wx3;
    acc[12]+= v3*wx0;  acc[13]+= v3*wx1;  acc[14]+= v3*wx2;  acc[15]+= v3*wx3;
  }
  { // tail: idx 1280..1295
    int idx = 1280 + lane;
    if (idx < NHW){
      int h = idx/36, ww = idx - h*36;
      float v = fp[idx];
      float v0 = v*sw[h], v1 = v*sw[36+h], v2 = v*sw[72+h], v3 = v*sw[108+h];
      float wx0 = sw[144+ww], wx1 = sw[180+ww], wx2 = sw[216+ww], wx3 = sw[252+ww];
      acc[0] += v0*wx0;  acc[1] += v0*wx1;  acc[2] += v0*wx2;  acc[3] += v0*wx3;
      acc[4] += v1*wx0;  acc[5] += v1*wx1;  acc[6] += v1*wx2;  acc[7] += v1*wx3;
      acc[8] += v2*wx0;  acc[9] += v2*wx1;  acc[10]+= v2*wx2;  acc[11]+= v2*wx3;
      acc[12]+= v3*wx0;  acc[13]+= v3*wx1;  acc[14]+= v3*wx2;  acc[15]+= v3*wx3;
    }
  }
  #pragma unroll
  for (int k=0;k<16;k++){
    float a = acc[k];
    #pragma unroll
    for (int off=32; off>0; off>>=1) a += __shfl_down(a, off);
    acc[k] = a;
  }
  if (lane == 0){
    float area = binw*binh;
    float ia = (area > 0.0f) ? 1.0f/fmaxf(area,1e-12f) : 0.0f;
    float4* kp = (float4*)(kflat + ((size_t)(b*256+c))*16);
    kp[0] = make_float4(acc[0]*ia, acc[1]*ia, acc[2]*ia, acc[3]*ia);
    kp[1] = make_float4(acc[4]*ia, acc[5]*ia, acc[6]*ia, acc[7]*ia);
    kp[2] = make_float4(acc[8]*ia, acc[9]*ia, acc[10]*ia, acc[11]*ia);
    kp[3] = make_float4(acc[12]*ia, acc[13]*ia, acc[14]*ia, acc[15]*ia);
  }
}

// ---- K2: pixel corr; 64 pixels/block, c-split over 4 waves + LDS combine
__global__ __launch_bounds__(256) void k_corr(const float* __restrict__ feat2,
    const float* __restrict__ kflat, float* __restrict__ corr,
    float* __restrict__ partial_se){
  int blk = blockIdx.x;          // b*21 + ch
  int b = blk / 21, ch = blk - b*21;
  int t = threadIdx.x, w = t >> 6, lane = t & 63;
  int pix = ch*64 + lane;
  bool act = pix < NHW;
  __shared__ float kl[4096];
  __shared__ float par[4][64][16];
  {
    const float4* src = (const float4*)(kflat + (size_t)b*4096);
    float4* dst = (float4*)kl;
    for (int i=t; i<1024; i+=256) dst[i] = src[i];
  }
  __syncthreads();
  float acc[16];
  #pragma unroll
  for (int k=0;k<16;k++) acc[k]=0.0f;
  if (act){
    const float* f2 = feat2 + (size_t)b*NCC*NHW + pix;
    for (int c=w*64; c<w*64+64; c++){
      float v = f2[(size_t)c*NHW];
      const float4* k4 = (const float4*)(&kl[c*16]);
      float4 ka = k4[0], kb = k4[1], kc = k4[2], kd = k4[3];
      acc[0]+=v*ka.x; acc[1]+=v*ka.y; acc[2]+=v*ka.z; acc[3]+=v*ka.w;
      acc[4]+=v*kb.x; acc[5]+=v*kb.y; acc[6]+=v*kb.z; acc[7]+=v*kb.w;
      acc[8]+=v*kc.x; acc[9]+=v*kc.y; acc[10]+=v*kc.z; acc[11]+=v*kc.w;
      acc[12]+=v*kd.x; acc[13]+=v*kd.y; acc[14]+=v*kd.z; acc[15]+=v*kd.w;
    }
  }
  {
    float4* pw4 = (float4*)par[w][lane];
    pw4[0] = make_float4(acc[0],acc[1],acc[2],acc[3]);
    pw4[1] = make_float4(acc[4],acc[5],acc[6],acc[7]);
    pw4[2] = make_float4(acc[8],acc[9],acc[10],acc[11]);
    pw4[3] = make_float4(acc[12],acc[13],acc[14],acc[15]);
  }
  __syncthreads();
  // thread (w,lane) combines k-range w*4..w*4+3 for pixel=lane
  float4 v0 = *(const float4*)&par[0][lane][w*4];
  float4 v1 = *(const float4*)&par[1][lane][w*4];
  float4 v2 = *(const float4*)&par[2][lane][w*4];
  float4 v3 = *(const float4*)&par[3][lane][w*4];
  float r0 = v0.x+v1.x+v2.x+v3.x;
  float r1 = v0.y+v1.y+v2.y+v3.y;
  float r2 = v0.z+v1.z+v2.z+v3.z;
  float r3 = v0.w+v1.w+v2.w+v3.w;
  if (act){
    float* cp = corr + (size_t)b*NK*NHW + pix;
    cp[(size_t)(w*4+0)*NHW] = r0;
    cp[(size_t)(w*4+1)*NHW] = r1;
    cp[(size_t)(w*4+2)*NHW] = r2;
    cp[(size_t)(w*4+3)*NHW] = r3;
  }
  // SE partial sums over this block's pixels (inactive lanes hold zeros)
  #pragma unroll
  for (int off=32; off>0; off>>=1){
    r0 += __shfl_down(r0, off);
    r1 += __shfl_down(r1, off);
    r2 += __shfl_down(r2, off);
    r3 += __shfl_down(r3, off);
  }
  if (lane == 0)
    *(float4*)&partial_se[(size_t)blk*16 + w*4] = make_float4(r0,r1,r2,r3);
}

// ---- K3: SE gate + theta / interleaved {phi,g}; 1 wave per 64 pixels ----
__global__ __launch_bounds__(64) void k_tpg(const float* __restrict__ corr,
    const float* __restrict__ partial_se,
    const float* __restrict__ w1, const float* __restrict__ w2,
    const float* __restrict__ tw, const float* __restrict__ tb,
    const float* __restrict__ pw, const float* __restrict__ pb,
    const float* __restrict__ gw, const float* __restrict__ gb,
    float* __restrict__ sscale,
    float* __restrict__ theta, float* __restrict__ pg){
  int blk = blockIdx.x;          // b*21 + ch
  int b = blk/21, ch = blk - b*21;
  int t = threadIdx.x;
  __shared__ float Wt[128], Wp[128], Wg[128], Bz[24], Ss[16], sS[16], sR[4];
  for (int i=t; i<128; i+=64){ Wt[i]=tw[i]; Wp[i]=pw[i]; Wg[i]=gw[i]; }
  if (t < 8){ Bz[t]=tb[t]; Bz[8+t]=pb[t]; Bz[16+t]=gb[t]; }
  if (t < 16){
    float a = 0.f;
    #pragma unroll
    for (int c2=0; c2<21; c2++) a += partial_se[(size_t)(b*21+c2)*16 + t];
    sS[t] = a * (1.0f/1296.0f);
  }
  __syncthreads();
  if (t < 4){
    float a=0.f;
    #pragma unroll
    for (int k=0;k<16;k++) a += sS[k]*w1[t*16+k];
    sR[t] = fmaxf(a, 0.f);
  }
  __syncthreads();
  if (t < 16){
    float a=0.f;
    #pragma unroll
    for (int j=0;j<4;j++) a += sR[j]*w2[t*4+j];
    float gsc = 1.0f/(1.0f+__expf(-a));
    Ss[t] = gsc;
    if (ch == 0) sscale[b*16+t] = gsc;
  }
  __syncthreads();
  int n = ch*64 + t;
  if (n >= NHW) return;
  float x[16];
  const float* cp = corr + (size_t)b*NK*NHW + n;
  #pragma unroll
  for (int c=0;c<16;c++) x[c] = cp[(size_t)c*NHW] * Ss[c];
  float th[8], ph[8], gg[8];
  #pragma unroll
  for (int o=0;o<8;o++){
    float a=Bz[o], p2=Bz[8+o], gq=Bz[16+o];
    #pragma unroll
    for (int c=0;c<16;c++){
      a  += Wt[o*16+c]*x[c];
      p2 += Wp[o*16+c]*x[c];
      gq += Wg[o*16+c]*x[c];
    }
    th[o]=a; ph[o]=p2; gg[o]=gq;
  }
  {
    float4* tp = (float4*)(theta + ((size_t)b*NHW + n)*8);
    tp[0] = make_float4(th[0],th[1],th[2],th[3]);
    tp[1] = make_float4(th[4],th[5],th[6],th[7]);
  }
  {
    float4* pp = (float4*)(pg + ((size_t)b*NHW + n)*16);
    pp[0] = make_float4(ph[0],ph[1],ph[2],ph[3]);
    pp[1] = make_float4(ph[4],ph[5],ph[6],ph[7]);
    pp[2] = make_float4(gg[0],gg[1],gg[2],gg[3]);
    pp[3] = make_float4(gg[4],gg[5],gg[6],gg[7]);
  }
}

// ---- K4: flash attention; 8-way key split, scalar row loads, pk-f32 -----
__global__ __launch_bounds__(512) void k_attn(const float* __restrict__ theta,
    const float* __restrict__ pg,
    const float* __restrict__ corr, const float* __restrict__ sscale,
    const float* __restrict__ Ww, const float* __restrict__ Wb,
    float* __restrict__ out){
  int blk = blockIdx.x;
  int b = blk / 21;
  int ch = blk - b*21;
  int t = threadIdx.x;
  int w = t >> 6;
  int lane = t & 63;
  int n = ch*64 + lane;
  bool act = n < NHW;
  __shared__ float sdat[4][64][13];
  __shared__ float syf[8][64];

  f32x2 t01, t23, t45, t67;
  {
    const float4* tp = (const float4*)(theta + ((size_t)b*NHW + (act ? n : 0))*8);
    float4 a0 = tp[0], a1 = tp[1];
    t01 = (f32x2){a0.x, a0.y} * LOG2E;
    t23 = (f32x2){a0.z, a0.w} * LOG2E;
    t45 = (f32x2){a1.x, a1.y} * LOG2E;
    t67 = (f32x2){a1.z, a1.w} * LOG2E;
  }
  float mr = -1e30f, l = 0.0f;
  f32x2 y01 = {0,0}, y23 = {0,0}, y45 = {0,0}, y67 = {0,0};

  int wu = __builtin_amdgcn_readfirstlane(w);
  const f32x16* pgb = (const f32x16*)(pg + (size_t)b*NHW*16);
  int j0 = wu*162;

  auto score = [&](const f32x16& r)->float{
    f32x2 a = t01 * (f32x2){r[0], r[1]};
    a = __builtin_elementwise_fma(t23, (f32x2){r[2], r[3]}, a);
    a = __builtin_elementwise_fma(t45, (f32x2){r[4], r[5]}, a);
    a = __builtin_elementwise_fma(t67, (f32x2){r[6], r[7]}, a);
    return a.x + a.y;
  };

  #pragma unroll 1
  for (int j = j0; j < j0+160; j += 4){
    f32x16 r0 = pgb[j+0];
    f32x16 r1 = pgb[j+1];
    f32x16 r2 = pgb[j+2];
    f32x16 r3 = pgb[j+3];
    float s0 = score(r0), s1 = score(r1), s2 = score(r2), s3 = score(r3);
    float cm = fmaxf(fmaxf(s0,s1), fmaxf(s2,s3));
    float mn = fmaxf(mr, cm);
    float cf = __builtin_amdgcn_exp2f(mr - mn);
    mr = mn;
    float p0 = __builtin_amdgcn_exp2f(s0 - mn);
    float p1 = __builtin_amdgcn_exp2f(s1 - mn);
    float p2 = __builtin_amdgcn_exp2f(s2 - mn);
    float p3 = __builtin_amdgcn_exp2f(s3 - mn);
    l = l*cf + ((p0+p1) + (p2+p3));
    f32x2 cfv = {cf,cf}, P0 = {p0,p0}, P1 = {p1,p1}, P2 = {p2,p2}, P3 = {p3,p3};
    y01 = __builtin_elementwise_fma(P0, (f32x2){r0[8], r0[9]}, y01*cfv);
    y01 = __builtin_elementwise_fma(P1, (f32x2){r1[8], r1[9]}, y01);
    y01 = __builtin_elementwise_fma(P2, (f32x2){r2[8], r2[9]}, y01);
    y01 = __builtin_elementwise_fma(P3, (f32x2){r3[8], r3[9]}, y01);
    y23 = __builtin_elementwise_fma(P0, (f32x2){r0[10], r0[11]}, y23*cfv);
    y23 = __builtin_elementwise_fma(P1, (f32x2){r1[10], r1[11]}, y23);
    y23 = __builtin_elementwise_fma(P2, (f32x2){r2[10], r2[11]}, y23);
    y23 = __builtin_elementwise_fma(P3, (f32x2){r3[10], r3[11]}, y23);
    y45 = __builtin_elementwise_fma(P0, (f32x2){r0[12], r0[13]}, y45*cfv);
    y45 = __builtin_elementwise_fma(P1, (f32x2){r1[12], r1[13]}, y45);
    y45 = __builtin_elementwise_fma(P2, (f32x2){r2[12], r2[13]}, y45);
    y45 = __builtin_elementwise_fma(P3, (f32x2){r3[12], r3[13]}, y45);
    y67 = __builtin_elementwise_fma(P0, (f32x2){r0[14], r0[15]}, y67*cfv);
    y67 = __builtin_elementwise_fma(P1, (f32x2){r1[14], r1[15]}, y67);
    y67 = __builtin_elementwise_fma(P2, (f32x2){r2[14], r2[15]}, y67);
    y67 = __builtin_elementwise_fma(P3, (f32x2){r3[14], r3[15]}, y67);
  }
  { // 2-key tail (162 = 40*4 + 2)
    int j = j0 + 160;
    f32x16 r0 = pgb[j+0];
    f32x16 r1 = pgb[j+1];
    float s0 = score(r0), s1 = score(r1);
    float cm = fmaxf(s0, s1);
    float mn = fmaxf(mr, cm);
    float cf = __builtin_amdgcn_exp2f(mr - mn);
    mr = mn;
    float p0 = __builtin_amdgcn_exp2f(s0 - mn);
    float p1 = __builtin_amdgcn_exp2f(s1 - mn);
    l = l*cf + (p0 + p1);
    f32x2 cfv = {cf,cf}, P0 = {p0,p0}, P1 = {p1,p1};
    y01 = __builtin_elementwise_fma(P0, (f32x2){r0[8], r0[9]}, y01*cfv);
    y01 = __builtin_elementwise_fma(P1, (f32x2){r1[8], r1[9]}, y01);
    y23 = __builtin_elementwise_fma(P0, (f32x2){r0[10], r0[11]}, y23*cfv);
    y23 = __builtin_elementwise_fma(P1, (f32x2){r1[10], r1[11]}, y23);
    y45 = __builtin_elementwise_fma(P0, (f32x2){r0[12], r0[13]}, y45*cfv);
    y45 = __builtin_elementwise_fma(P1, (f32x2){r1[12], r1[13]}, y45);
    y67 = __builtin_elementwise_fma(P0, (f32x2){r0[14], r0[15]}, y67*cfv);
    y67 = __builtin_elementwise_fma(P1, (f32x2){r1[14], r1[15]}, y67);
  }

  float y[8] = {y01.x,y01.y,y23.x,y23.y,y45.x,y45.y,y67.x,y67.y};

  // 3-stage tree merge: {4..7}->{0..3}, {2,3}->{0,1}, {1}->{0}
  if (w >= 4){
    float* d = sdat[w-4][lane];
    d[0]=mr; d[1]=l;
    #pragma unroll
    for (int o=0;o<8;o++) d[2+o]=y[o];
  }
  __syncthreads();
  if (w < 4){
    const float* d = sdat[w][lane];
    float m2=d[0], l2=d[1];
    float mm = fmaxf(mr, m2);
    float c1 = __builtin_amdgcn_exp2f(mr-mm), c2 = __builtin_amdgcn_exp2f(m2-mm);
    mr = mm; l = l*c1 + l2*c2;
    #pragma unroll
    for (int o=0;o<8;o++) y[o] = y[o]*c1 + d[2+o]*c2;
  }
  __syncthreads();
  if (w == 2 || w == 3){
    float* d = sdat[w-2][lane];
    d[0]=mr; d[1]=l;
    #pragma unroll
    for (int o=0;o<8;o++) d[2+o]=y[o];
  }
  __syncthreads();
  if (w < 2){
    const float* d = sdat[w][lane];
    float m2=d[0], l2=d[1];
    float mm = fmaxf(mr, m2);
    float c1 = __builtin_amdgcn_exp2f(mr-mm), c2 = __builtin_amdgcn_exp2f(m2-mm);
    mr = mm; l = l*c1 + l2*c2;
    #pragma unroll
    for (int o=0;o<8;o++) y[o] = y[o]*c1 + d[2+o]*c2;
  }
  __syncthreads();
  if (w == 1){
    float* d = sdat[0][lane];
    d[0]=mr; d[1]=l;
    #pragma unroll
    for (int o=0;o<8;o++) d[2+o]=y[o];
  }
  __syncthreads();
  if (w == 0){
    const float* d = sdat[0][lane];
    float m2=d[0], l2=d[1];
    float mm = fmaxf(mr, m2);
    float c1 = __builtin_amdgcn_exp2f(mr-mm), c2 = __builtin_amdgcn_exp2f(m2-mm);
    l = l*c1 + l2*c2;
    float invl = 1.0f / l;
    #pragma unroll
    for (int o=0;o<8;o++) syf[o][lane] = (y[o]*c1 + d[2+o]*c2)*invl;
  }
  __syncthreads();

  // epilogue: each of 8 waves handles 2 output channels
  if (act){
    float yv[8];
    #pragma unroll
    for (int o=0;o<8;o++) yv[o] = syf[o][lane];
    const float* cp = corr + (size_t)b*NK*NHW + n;
    const float* ss = sscale + b*16;
    float* op = out + (size_t)b*NK*NHW + n;
    #pragma unroll
    for (int q=0;q<2;q++){
      int c2 = w*2+q;
      float z = Wb[c2];
      #pragma unroll
      for (int o=0;o<8;o++) z += Ww[c2*8+o]*yv[o];
      op[(size_t)c2*NHW] = z + cp[(size_t)c2*NHW]*ss[c2];
    }
  }
}

extern "C" void kernel_launch(void* const* d_in, const int* in_sizes, int n_in,
                              void* d_out, int out_size, void* d_ws, size_t ws_size,
                              hipStream_t stream){
  const float* feat1 = (const float*)d_in[0];
  const float* feat2 = (const float*)d_in[1];
  const float* bb1   = (const float*)d_in[2];
  const float* se_w1 = (const float*)d_in[3];
  const float* se_w2 = (const float*)d_in[4];
  const float* tw    = (const float*)d_in[5];
  const float* tb    = (const float*)d_in[6];
  const float* pw    = (const float*)d_in[7];
  const float* pb    = (const float*)d_in[8];
  const float* gw    = (const float*)d_in[9];
  const float* gb    = (const float*)d_in[10];
  const float* Ww    = (const float*)d_in[11];
  const float* Wb    = (const float*)d_in[12];
  float* out = (float*)d_out;

  float* ws = (float*)d_ws;
  float* kflat      = ws;                                // 64*256*16
  float* corr       = kflat + 64*256*16;                 // 64*16*1296
  float* partial_se = corr + (size_t)64*16*1296;         // 64*21*16
  float* sscale     = partial_se + 64*21*16;             // 64*16
  float* theta      = sscale + 64*16;                    // 64*1296*8
  float* pg         = theta + (size_t)64*1296*8;         // 64*1296*16

  hipLaunchKernelGGL(k_prpool, dim3(64*64), dim3(256), 0, stream, feat1, bb1, kflat);
  hipLaunchKernelGGL(k_corr, dim3(64*21), dim3(256), 0, stream, feat2, kflat, corr, partial_se);
  hipLaunchKernelGGL(k_tpg, dim3(64*21), dim3(64), 0, stream, corr, partial_se,
                     se_w1, se_w2, tw, tb, pw, pb, gw, gb, sscale, theta, pg);
  hipLaunchKernelGGL(k_attn, dim3(64*21), dim3(512), 0, stream, theta, pg, corr, sscale, Ww, Wb, out);
}

// Round 5
// 132.553 us; speedup vs baseline: 2.6557x; 1.2315x over previous
//
#include <hip/hip_runtime.h>
#include <cmath>

#define NB 64
#define NCC 256
#define NH 36
#define NW 36
#define NHW 1296
#define NK 16
#define NI 8
#define SC (1.0f/16.0f)
#define LOG2E 1.4426950408889634f

typedef __attribute__((ext_vector_type(16))) float f32x16;
typedef __attribute__((ext_vector_type(4)))  float f32x4;
typedef __attribute__((ext_vector_type(2)))  float f32x2;

__device__ __forceinline__ float hatc(float t){
  t = fminf(fmaxf(t, -1.0f), 1.0f);
  float a = 1.0f + t, bq = 1.0f - t;
  return (t < 0.0f) ? 0.5f*a*a : 1.0f - 0.5f*bq*bq;
}

// ---- K1: PrRoI pooling; 1 wave per (b,c); float4 feature loads ----------
__global__ __launch_bounds__(256) void k_prpool(const float* __restrict__ feat1,
    const float* __restrict__ bb1, float* __restrict__ kflat){
  int blk = blockIdx.x;          // b*64 + cg
  int b = blk >> 6, cg = blk & 63;
  int t = threadIdx.x, w = t >> 6, lane = t & 63;
  int c = cg*4 + w;
  __shared__ float4 wY4[36];
  __shared__ float  wXp[36*5];   // stride-5 to spread banks
  float bx = bb1[b*4+0], by = bb1[b*4+1], bwv = bb1[b*4+2], bhv = bb1[b*4+3];
  float x1 = bx*SC, y1 = by*SC;
  float binw = bwv*SC*0.25f, binh = bhv*SC*0.25f;
  if (t < 36){
    float fi = (float)t;
    float4 r;
    r.x = hatc(y1 + 1.0f*binh - fi) - hatc(y1 + 0.0f*binh - fi);
    r.y = hatc(y1 + 2.0f*binh - fi) - hatc(y1 + 1.0f*binh - fi);
    r.z = hatc(y1 + 3.0f*binh - fi) - hatc(y1 + 2.0f*binh - fi);
    r.w = hatc(y1 + 4.0f*binh - fi) - hatc(y1 + 3.0f*binh - fi);
    wY4[t] = r;
  } else if (t < 72){
    int i = t - 36;
    float fi = (float)i;
    wXp[i*5+0] = hatc(x1 + 1.0f*binw - fi) - hatc(x1 + 0.0f*binw - fi);
    wXp[i*5+1] = hatc(x1 + 2.0f*binw - fi) - hatc(x1 + 1.0f*binw - fi);
    wXp[i*5+2] = hatc(x1 + 3.0f*binw - fi) - hatc(x1 + 2.0f*binw - fi);
    wXp[i*5+3] = hatc(x1 + 4.0f*binw - fi) - hatc(x1 + 3.0f*binw - fi);
  }
  __syncthreads();
  f32x4 acc4[4];
  #pragma unroll
  for (int p=0;p<4;p++) acc4[p] = (f32x4){0,0,0,0};
  const float4* fp4 = (const float4*)(feat1 + ((size_t)(b*256+c))*NHW);

  auto body = [&](float4 v, int px){
    #pragma unroll
    for (int j=0;j<4;j++){
      int p = px + j;
      int h = p/36, x = p - h*36;
      float vj = (j==0)?v.x:(j==1)?v.y:(j==2)?v.z:v.w;
      float4 wy = wY4[h];
      f32x4 wxv = {wXp[x*5+0], wXp[x*5+1], wXp[x*5+2], wXp[x*5+3]};
      f32x4 a0 = {vj*wy.x, vj*wy.x, vj*wy.x, vj*wy.x};
      f32x4 a1 = {vj*wy.y, vj*wy.y, vj*wy.y, vj*wy.y};
      f32x4 a2 = {vj*wy.z, vj*wy.z, vj*wy.z, vj*wy.z};
      f32x4 a3 = {vj*wy.w, vj*wy.w, vj*wy.w, vj*wy.w};
      acc4[0] = __builtin_elementwise_fma(a0, wxv, acc4[0]);
      acc4[1] = __builtin_elementwise_fma(a1, wxv, acc4[1]);
      acc4[2] = __builtin_elementwise_fma(a2, wxv, acc4[2]);
      acc4[3] = __builtin_elementwise_fma(a3, wxv, acc4[3]);
    }
  };

  #pragma unroll
  for (int i=0;i<5;i++){
    int f4i = i*64 + lane;            // 320 f4 = 1280 px
    float4 v = fp4[f4i];
    body(v, f4i*4);
  }
  if (lane < 4){                       // tail: f4 320..323 (px 1280..1295)
    int f4i = 320 + lane;
    float4 v = fp4[f4i];
    body(v, f4i*4);
  }
  float accf[16];
  #pragma unroll
  for (int p=0;p<4;p++){
    accf[p*4+0]=acc4[p].x; accf[p*4+1]=acc4[p].y;
    accf[p*4+2]=acc4[p].z; accf[p*4+3]=acc4[p].w;
  }
  #pragma unroll
  for (int k=0;k<16;k++){
    float a = accf[k];
    #pragma unroll
    for (int off=32; off>0; off>>=1) a += __shfl_down(a, off);
    accf[k] = a;
  }
  if (lane == 0){
    float area = binw*binh;
    float ia = (area > 0.0f) ? 1.0f/fmaxf(area,1e-12f) : 0.0f;
    float4* kp = (float4*)(kflat + ((size_t)(b*256+c))*16);
    kp[0] = make_float4(accf[0]*ia, accf[1]*ia, accf[2]*ia, accf[3]*ia);
    kp[1] = make_float4(accf[4]*ia, accf[5]*ia, accf[6]*ia, accf[7]*ia);
    kp[2] = make_float4(accf[8]*ia, accf[9]*ia, accf[10]*ia, accf[11]*ia);
    kp[3] = make_float4(accf[12]*ia, accf[13]*ia, accf[14]*ia, accf[15]*ia);
  }
}

// ---- K2: pixel corr; float4 pixel loads, 8-way channel split ------------
// block = 512 thr (8 waves) over 216 pixels; wave w: channels w*32..w*32+31
__global__ __launch_bounds__(512) void k_corr(const float* __restrict__ feat2,
    const float* __restrict__ kflat, float* __restrict__ corr,
    float* __restrict__ partial_se){
  int blk = blockIdx.x;          // b*6 + ch
  int b = blk / 6, ch = blk - b*6;
  int t = threadIdx.x, w = t >> 6, lane = t & 63;
  int px0 = ch*216;              // 54 float4 per chunk
  __shared__ float par[4][16][216];

  int wu = __builtin_amdgcn_readfirstlane(w);
  int c0 = wu*32;
  int l4 = (lane < 54) ? lane : 53;   // lanes 54..63 duplicate lane 53 (benign)

  f32x4 acc[16];
  #pragma unroll
  for (int k=0;k<16;k++) acc[k] = (f32x4){0,0,0,0};

  const float* f2base = feat2 + (size_t)b*NCC*NHW + px0 + l4*4;
  const float* kfb = kflat + (size_t)b*4096;
  #pragma unroll 4
  for (int c = c0; c < c0+32; ++c){
    f32x4 r = *(const f32x4*)(f2base + (size_t)c*NHW);
    f32x16 kf = *(const f32x16*)(kfb + c*16);      // uniform -> s_load
    #pragma unroll
    for (int k=0;k<16;k++){
      f32x4 kv = {kf[k], kf[k], kf[k], kf[k]};
      acc[k] = __builtin_elementwise_fma(r, kv, acc[k]);
    }
  }

  // phase 1: waves 4..7 deposit
  if (w >= 4){
    #pragma unroll
    for (int k=0;k<16;k++)
      *(f32x4*)&par[w-4][k][l4*4] = acc[k];
  }
  __syncthreads();
  // phase 2: waves 0..3 add and store back
  if (w < 4){
    #pragma unroll
    for (int k=0;k<16;k++){
      f32x4 tmp = *(const f32x4*)&par[w][k][l4*4];
      *(f32x4*)&par[w][k][l4*4] = tmp + acc[k];
    }
  }
  __syncthreads();
  // phase 3: combine 4 buffers; 32 consecutive lanes share one k
  int k = (w<<1) | (lane>>5);
  int j0 = lane & 31;
  float se_r = 0.0f;
  float* cp = corr + (size_t)b*NK*NHW + (size_t)k*NHW + px0;
  for (int jj=j0; jj<54; jj+=32){
    f32x4 s = *(const f32x4*)&par[0][k][jj*4];
    s += *(const f32x4*)&par[1][k][jj*4];
    s += *(const f32x4*)&par[2][k][jj*4];
    s += *(const f32x4*)&par[3][k][jj*4];
    *(f32x4*)(cp + jj*4) = s;
    se_r += (s.x+s.y) + (s.z+s.w);
  }
  #pragma unroll
  for (int off=16; off>0; off>>=1) se_r += __shfl_down(se_r, off, 32);
  if (j0 == 0)
    partial_se[(size_t)blk*16 + k] = se_r;
}

// ---- K3: SE gate + theta / interleaved {phi,g}; 1 wave per 64 pixels ----
__global__ __launch_bounds__(64) void k_tpg(const float* __restrict__ corr,
    const float* __restrict__ partial_se,
    const float* __restrict__ w1, const float* __restrict__ w2,
    const float* __restrict__ tw, const float* __restrict__ tb,
    const float* __restrict__ pw, const float* __restrict__ pb,
    const float* __restrict__ gw, const float* __restrict__ gb,
    float* __restrict__ sscale,
    float* __restrict__ theta, float* __restrict__ pg){
  int blk = blockIdx.x;          // b*21 + ch
  int b = blk/21, ch = blk - b*21;
  int t = threadIdx.x;
  __shared__ float Wt[128], Wp[128], Wg[128], Bz[24], Ss[16], sS[16], sR[4];
  for (int i=t; i<128; i+=64){ Wt[i]=tw[i]; Wp[i]=pw[i]; Wg[i]=gw[i]; }
  if (t < 8){ Bz[t]=tb[t]; Bz[8+t]=pb[t]; Bz[16+t]=gb[t]; }
  if (t < 16){
    float a = 0.f;
    #pragma unroll
    for (int c2=0; c2<6; c2++) a += partial_se[(size_t)(b*6+c2)*16 + t];
    sS[t] = a * (1.0f/1296.0f);
  }
  __syncthreads();
  if (t < 4){
    float a=0.f;
    #pragma unroll
    for (int k=0;k<16;k++) a += sS[k]*w1[t*16+k];
    sR[t] = fmaxf(a, 0.f);
  }
  __syncthreads();
  if (t < 16){
    float a=0.f;
    #pragma unroll
    for (int j=0;j<4;j++) a += sR[j]*w2[t*4+j];
    float gsc = 1.0f/(1.0f+__expf(-a));
    Ss[t] = gsc;
    if (ch == 0) sscale[b*16+t] = gsc;
  }
  __syncthreads();
  int n = ch*64 + t;
  if (n >= NHW) return;
  float x[16];
  const float* cp = corr + (size_t)b*NK*NHW + n;
  #pragma unroll
  for (int c=0;c<16;c++) x[c] = cp[(size_t)c*NHW] * Ss[c];
  float th[8], ph[8], gg[8];
  #pragma unroll
  for (int o=0;o<8;o++){
    float a=Bz[o], p2=Bz[8+o], gq=Bz[16+o];
    #pragma unroll
    for (int c=0;c<16;c++){
      a  += Wt[o*16+c]*x[c];
      p2 += Wp[o*16+c]*x[c];
      gq += Wg[o*16+c]*x[c];
    }
    th[o]=a; ph[o]=p2; gg[o]=gq;
  }
  {
    float4* tp = (float4*)(theta + ((size_t)b*NHW + n)*8);
    tp[0] = make_float4(th[0],th[1],th[2],th[3]);
    tp[1] = make_float4(th[4],th[5],th[6],th[7]);
  }
  {
    float4* pp = (float4*)(pg + ((size_t)b*NHW + n)*16);
    pp[0] = make_float4(ph[0],ph[1],ph[2],ph[3]);
    pp[1] = make_float4(ph[4],ph[5],ph[6],ph[7]);
    pp[2] = make_float4(gg[0],gg[1],gg[2],gg[3]);
    pp[3] = make_float4(gg[4],gg[5],gg[6],gg[7]);
  }
}

// ---- K4: flash attention; 8-way key split, scalar row loads, pk-f32 -----
__global__ __launch_bounds__(512) void k_attn(const float* __restrict__ theta,
    const float* __restrict__ pg,
    const float* __restrict__ corr, const float* __restrict__ sscale,
    const float* __restrict__ Ww, const float* __restrict__ Wb,
    float* __restrict__ out){
  int blk = blockIdx.x;
  int b = blk / 21;
  int ch = blk - b*21;
  int t = threadIdx.x;
  int w = t >> 6;
  int lane = t & 63;
  int n = ch*64 + lane;
  bool act = n < NHW;
  __shared__ float sdat[4][64][13];
  __shared__ float syf[8][64];

  f32x2 t01, t23, t45, t67;
  {
    const float4* tp = (const float4*)(theta + ((size_t)b*NHW + (act ? n : 0))*8);
    float4 a0 = tp[0], a1 = tp[1];
    t01 = (f32x2){a0.x, a0.y} * LOG2E;
    t23 = (f32x2){a0.z, a0.w} * LOG2E;
    t45 = (f32x2){a1.x, a1.y} * LOG2E;
    t67 = (f32x2){a1.z, a1.w} * LOG2E;
  }
  float mr = -1e30f, l = 0.0f;
  f32x2 y01 = {0,0}, y23 = {0,0}, y45 = {0,0}, y67 = {0,0};

  int wu = __builtin_amdgcn_readfirstlane(w);
  const f32x16* pgb = (const f32x16*)(pg + (size_t)b*NHW*16);
  int j0 = wu*162;

  auto score = [&](const f32x16& r)->float{
    f32x2 a = t01 * (f32x2){r[0], r[1]};
    a = __builtin_elementwise_fma(t23, (f32x2){r[2], r[3]}, a);
    a = __builtin_elementwise_fma(t45, (f32x2){r[4], r[5]}, a);
    a = __builtin_elementwise_fma(t67, (f32x2){r[6], r[7]}, a);
    return a.x + a.y;
  };

  #pragma unroll 1
  for (int j = j0; j < j0+160; j += 4){
    f32x16 r0 = pgb[j+0];
    f32x16 r1 = pgb[j+1];
    f32x16 r2 = pgb[j+2];
    f32x16 r3 = pgb[j+3];
    float s0 = score(r0), s1 = score(r1), s2 = score(r2), s3 = score(r3);
    float cm = fmaxf(fmaxf(s0,s1), fmaxf(s2,s3));
    float mn = fmaxf(mr, cm);
    float cf = __builtin_amdgcn_exp2f(mr - mn);
    mr = mn;
    float p0 = __builtin_amdgcn_exp2f(s0 - mn);
    float p1 = __builtin_amdgcn_exp2f(s1 - mn);
    float p2 = __builtin_amdgcn_exp2f(s2 - mn);
    float p3 = __builtin_amdgcn_exp2f(s3 - mn);
    l = l*cf + ((p0+p1) + (p2+p3));
    f32x2 cfv = {cf,cf}, P0 = {p0,p0}, P1 = {p1,p1}, P2 = {p2,p2}, P3 = {p3,p3};
    y01 = __builtin_elementwise_fma(P0, (f32x2){r0[8], r0[9]}, y01*cfv);
    y01 = __builtin_elementwise_fma(P1, (f32x2){r1[8], r1[9]}, y01);
    y01 = __builtin_elementwise_fma(P2, (f32x2){r2[8], r2[9]}, y01);
    y01 = __builtin_elementwise_fma(P3, (f32x2){r3[8], r3[9]}, y01);
    y23 = __builtin_elementwise_fma(P0, (f32x2){r0[10], r0[11]}, y23*cfv);
    y23 = __builtin_elementwise_fma(P1, (f32x2){r1[10], r1[11]}, y23);
    y23 = __builtin_elementwise_fma(P2, (f32x2){r2[10], r2[11]}, y23);
    y23 = __builtin_elementwise_fma(P3, (f32x2){r3[10], r3[11]}, y23);
    y45 = __builtin_elementwise_fma(P0, (f32x2){r0[12], r0[13]}, y45*cfv);
    y45 = __builtin_elementwise_fma(P1, (f32x2){r1[12], r1[13]}, y45);
    y45 = __builtin_elementwise_fma(P2, (f32x2){r2[12], r2[13]}, y45);
    y45 = __builtin_elementwise_fma(P3, (f32x2){r3[12], r3[13]}, y45);
    y67 = __builtin_elementwise_fma(P0, (f32x2){r0[14], r0[15]}, y67*cfv);
    y67 = __builtin_elementwise_fma(P1, (f32x2){r1[14], r1[15]}, y67);
    y67 = __builtin_elementwise_fma(P2, (f32x2){r2[14], r2[15]}, y67);
    y67 = __builtin_elementwise_fma(P3, (f32x2){r3[14], r3[15]}, y67);
  }
  { // 2-key tail (162 = 40*4 + 2)
    int j = j0 + 160;
    f32x16 r0 = pgb[j+0];
    f32x16 r1 = pgb[j+1];
    float s0 = score(r0), s1 = score(r1);
    float cm = fmaxf(s0, s1);
    float mn = fmaxf(mr, cm);
    float cf = __builtin_amdgcn_exp2f(mr - mn);
    mr = mn;
    float p0 = __builtin_amdgcn_exp2f(s0 - mn);
    float p1 = __builtin_amdgcn_exp2f(s1 - mn);
    l = l*cf + (p0 + p1);
    f32x2 cfv = {cf,cf}, P0 = {p0,p0}, P1 = {p1,p1};
    y01 = __builtin_elementwise_fma(P0, (f32x2){r0[8], r0[9]}, y01*cfv);
    y01 = __builtin_elementwise_fma(P1, (f32x2){r1[8], r1[9]}, y01);
    y23 = __builtin_elementwise_fma(P0, (f32x2){r0[10], r0[11]}, y23*cfv);
    y23 = __builtin_elementwise_fma(P1, (f32x2){r1[10], r1[11]}, y23);
    y45 = __builtin_elementwise_fma(P0, (f32x2){r0[12], r0[13]}, y45*cfv);
    y45 = __builtin_elementwise_fma(P1, (f32x2){r1[12], r1[13]}, y45);
    y67 = __builtin_elementwise_fma(P0, (f32x2){r0[14], r0[15]}, y67*cfv);
    y67 = __builtin_elementwise_fma(P1, (f32x2){r1[14], r1[15]}, y67);
  }

  float y[8] = {y01.x,y01.y,y23.x,y23.y,y45.x,y45.y,y67.x,y67.y};

  // 3-stage tree merge: {4..7}->{0..3}, {2,3}->{0,1}, {1}->{0}
  if (w >= 4){
    float* d = sdat[w-4][lane];
    d[0]=mr; d[1]=l;
    #pragma unroll
    for (int o=0;o<8;o++) d[2+o]=y[o];
  }
  __syncthreads();
  if (w < 4){
    const float* d = sdat[w][lane];
    float m2=d[0], l2=d[1];
    float mm = fmaxf(mr, m2);
    float c1 = __builtin_amdgcn_exp2f(mr-mm), c2 = __builtin_amdgcn_exp2f(m2-mm);
    mr = mm; l = l*c1 + l2*c2;
    #pragma unroll
    for (int o=0;o<8;o++) y[o] = y[o]*c1 + d[2+o]*c2;
  }
  __syncthreads();
  if (w == 2 || w == 3){
    float* d = sdat[w-2][lane];
    d[0]=mr; d[1]=l;
    #pragma unroll
    for (int o=0;o<8;o++) d[2+o]=y[o];
  }
  __syncthreads();
  if (w < 2){
    const float* d = sdat[w][lane];
    float m2=d[0], l2=d[1];
    float mm = fmaxf(mr, m2);
    float c1 = __builtin_amdgcn_exp2f(mr-mm), c2 = __builtin_amdgcn_exp2f(m2-mm);
    mr = mm; l = l*c1 + l2*c2;
    #pragma unroll
    for (int o=0;o<8;o++) y[o] = y[o]*c1 + d[2+o]*c2;
  }
  __syncthreads();
  if (w == 1){
    float* d = sdat[0][lane];
    d[0]=mr; d[1]=l;
    #pragma unroll
    for (int o=0;o<8;o++) d[2+o]=y[o];
  }
  __syncthreads();
  if (w == 0){
    const float* d = sdat[0][lane];
    float m2=d[0], l2=d[1];
    float mm = fmaxf(mr, m2);
    float c1 = __builtin_amdgcn_exp2f(mr-mm), c2 = __builtin_amdgcn_exp2f(m2-mm);
    l = l*c1 + l2*c2;
    float invl = 1.0f / l;
    #pragma unroll
    for (int o=0;o<8;o++) syf[o][lane] = (y[o]*c1 + d[2+o]*c2)*invl;
  }
  __syncthreads();

  // epilogue: each of 8 waves handles 2 output channels
  if (act){
    float yv[8];
    #pragma unroll
    for (int o=0;o<8;o++) yv[o] = syf[o][lane];
    const float* cp = corr + (size_t)b*NK*NHW + n;
    const float* ss = sscale + b*16;
    float* op = out + (size_t)b*NK*NHW + n;
    #pragma unroll
    for (int q=0;q<2;q++){
      int c2 = w*2+q;
      float z = Wb[c2];
      #pragma unroll
      for (int o=0;o<8;o++) z += Ww[c2*8+o]*yv[o];
      op[(size_t)c2*NHW] = z + cp[(size_t)c2*NHW]*ss[c2];
    }
  }
}

extern "C" void kernel_launch(void* const* d_in, const int* in_sizes, int n_in,
                              void* d_out, int out_size, void* d_ws, size_t ws_size,
                              hipStream_t stream){
  const float* feat1 = (const float*)d_in[0];
  const float* feat2 = (const float*)d_in[1];
  const float* bb1   = (const float*)d_in[2];
  const float* se_w1 = (const float*)d_in[3];
  const float* se_w2 = (const float*)d_in[4];
  const float* tw    = (const float*)d_in[5];
  const float* tb    = (const float*)d_in[6];
  const float* pw    = (const float*)d_in[7];
  const float* pb    = (const float*)d_in[8];
  const float* gw    = (const float*)d_in[9];
  const float* gb    = (const float*)d_in[10];
  const float* Ww    = (const float*)d_in[11];
  const float* Wb    = (const float*)d_in[12];
  float* out = (float*)d_out;

  float* ws = (float*)d_ws;
  float* kflat      = ws;                                // 64*256*16
  float* corr       = kflat + 64*256*16;                 // 64*16*1296
  float* partial_se = corr + (size_t)64*16*1296;         // 64*6*16
  float* sscale     = partial_se + 64*6*16;              // 64*16
  float* theta      = sscale + 64*16;                    // 64*1296*8
  float* pg         = theta + (size_t)64*1296*8;         // 64*1296*16

  hipLaunchKernelGGL(k_prpool, dim3(64*64), dim3(256), 0, stream, feat1, bb1, kflat);
  hipLaunchKernelGGL(k_corr, dim3(64*6), dim3(512), 0, stream, feat2, kflat, corr, partial_se);
  hipLaunchKernelGGL(k_tpg, dim3(64*21), dim3(64), 0, stream, corr, partial_se,
                     se_w1, se_w2, tw, tb, pw, pb, gw, gb, sscale, theta, pg);
  hipLaunchKernelGGL(k_attn, dim3(64*21), dim3(512), 0, stream, theta, pg, corr, sscale, Ww, Wb, out);
}

// Round 6
// 123.037 us; speedup vs baseline: 2.8611x; 1.0773x over previous
//
#include <hip/hip_runtime.h>
#include <cmath>

#define NB 64
#define NCC 256
#define NH 36
#define NW 36
#define NHW 1296
#define NK 16
#define NI 8
#define SC (1.0f/16.0f)
#define LOG2E 1.4426950408889634f
#define NPAD 1312   // 41*32

typedef __attribute__((ext_vector_type(16))) float f32x16;
typedef __attribute__((ext_vector_type(4)))  float f32x4;
typedef __attribute__((ext_vector_type(4)))  short s16x4;
typedef __attribute__((ext_vector_type(8)))  unsigned short u16x8;
typedef __attribute__((ext_vector_type(2)))  unsigned int u32x2;

__device__ __forceinline__ float hatc(float t){
  t = fminf(fmaxf(t, -1.0f), 1.0f);
  float a = 1.0f + t, bq = 1.0f - t;
  return (t < 0.0f) ? 0.5f*a*a : 1.0f - 0.5f*bq*bq;
}

__device__ __forceinline__ unsigned short bf16rn(float f){
  unsigned int u = __builtin_bit_cast(unsigned int, f);
  return (unsigned short)((u + 0x7FFFu + ((u >> 16) & 1u)) >> 16);
}
__device__ __forceinline__ float bf16tof(unsigned short h){
  unsigned int u = ((unsigned int)h) << 16;
  return __builtin_bit_cast(float, u);
}

// ---- K1: PrRoI pooling; 1 wave per (b,c); float4 feature loads ----------
__global__ __launch_bounds__(256) void k_prpool(const float* __restrict__ feat1,
    const float* __restrict__ bb1, float* __restrict__ kflat){
  int blk = blockIdx.x;          // b*64 + cg
  int b = blk >> 6, cg = blk & 63;
  int t = threadIdx.x, w = t >> 6, lane = t & 63;
  int c = cg*4 + w;
  __shared__ float4 wY4[36];
  __shared__ float  wXp[36*5];
  float bx = bb1[b*4+0], by = bb1[b*4+1], bwv = bb1[b*4+2], bhv = bb1[b*4+3];
  float x1 = bx*SC, y1 = by*SC;
  float binw = bwv*SC*0.25f, binh = bhv*SC*0.25f;
  if (t < 36){
    float fi = (float)t;
    float4 r;
    r.x = hatc(y1 + 1.0f*binh - fi) - hatc(y1 + 0.0f*binh - fi);
    r.y = hatc(y1 + 2.0f*binh - fi) - hatc(y1 + 1.0f*binh - fi);
    r.z = hatc(y1 + 3.0f*binh - fi) - hatc(y1 + 2.0f*binh - fi);
    r.w = hatc(y1 + 4.0f*binh - fi) - hatc(y1 + 3.0f*binh - fi);
    wY4[t] = r;
  } else if (t < 72){
    int i = t - 36;
    float fi = (float)i;
    wXp[i*5+0] = hatc(x1 + 1.0f*binw - fi) - hatc(x1 + 0.0f*binw - fi);
    wXp[i*5+1] = hatc(x1 + 2.0f*binw - fi) - hatc(x1 + 1.0f*binw - fi);
    wXp[i*5+2] = hatc(x1 + 3.0f*binw - fi) - hatc(x1 + 2.0f*binw - fi);
    wXp[i*5+3] = hatc(x1 + 4.0f*binw - fi) - hatc(x1 + 3.0f*binw - fi);
  }
  __syncthreads();
  f32x4 acc4[4];
  #pragma unroll
  for (int p=0;p<4;p++) acc4[p] = (f32x4){0,0,0,0};
  const float4* fp4 = (const float4*)(feat1 + ((size_t)(b*256+c))*NHW);

  auto body = [&](float4 v, int px){
    #pragma unroll
    for (int j=0;j<4;j++){
      int p = px + j;
      int h = p/36, x = p - h*36;
      float vj = (j==0)?v.x:(j==1)?v.y:(j==2)?v.z:v.w;
      float4 wy = wY4[h];
      f32x4 wxv = {wXp[x*5+0], wXp[x*5+1], wXp[x*5+2], wXp[x*5+3]};
      f32x4 a0 = {vj*wy.x, vj*wy.x, vj*wy.x, vj*wy.x};
      f32x4 a1 = {vj*wy.y, vj*wy.y, vj*wy.y, vj*wy.y};
      f32x4 a2 = {vj*wy.z, vj*wy.z, vj*wy.z, vj*wy.z};
      f32x4 a3 = {vj*wy.w, vj*wy.w, vj*wy.w, vj*wy.w};
      acc4[0] = __builtin_elementwise_fma(a0, wxv, acc4[0]);
      acc4[1] = __builtin_elementwise_fma(a1, wxv, acc4[1]);
      acc4[2] = __builtin_elementwise_fma(a2, wxv, acc4[2]);
      acc4[3] = __builtin_elementwise_fma(a3, wxv, acc4[3]);
    }
  };

  #pragma unroll
  for (int i=0;i<5;i++){
    int f4i = i*64 + lane;
    float4 v = fp4[f4i];
    body(v, f4i*4);
  }
  if (lane < 4){
    int f4i = 320 + lane;
    float4 v = fp4[f4i];
    body(v, f4i*4);
  }
  float accf[16];
  #pragma unroll
  for (int p=0;p<4;p++){
    accf[p*4+0]=acc4[p].x; accf[p*4+1]=acc4[p].y;
    accf[p*4+2]=acc4[p].z; accf[p*4+3]=acc4[p].w;
  }
  #pragma unroll
  for (int k=0;k<16;k++){
    float a = accf[k];
    #pragma unroll
    for (int off=32; off>0; off>>=1) a += __shfl_down(a, off);
    accf[k] = a;
  }
  if (lane == 0){
    float area = binw*binh;
    float ia = (area > 0.0f) ? 1.0f/fmaxf(area,1e-12f) : 0.0f;
    float4* kp = (float4*)(kflat + ((size_t)(b*256+c))*16);
    kp[0] = make_float4(accf[0]*ia, accf[1]*ia, accf[2]*ia, accf[3]*ia);
    kp[1] = make_float4(accf[4]*ia, accf[5]*ia, accf[6]*ia, accf[7]*ia);
    kp[2] = make_float4(accf[8]*ia, accf[9]*ia, accf[10]*ia, accf[11]*ia);
    kp[3] = make_float4(accf[12]*ia, accf[13]*ia, accf[14]*ia, accf[15]*ia);
  }
}

// ---- K2: pixel corr; float4 pixel loads, 8-way channel split ------------
__global__ __launch_bounds__(512) void k_corr(const float* __restrict__ feat2,
    const float* __restrict__ kflat, float* __restrict__ corr,
    float* __restrict__ partial_se){
  int blk = blockIdx.x;          // b*6 + ch
  int b = blk / 6, ch = blk - b*6;
  int t = threadIdx.x, w = t >> 6, lane = t & 63;
  int px0 = ch*216;
  __shared__ float par[4][16][216];

  int wu = __builtin_amdgcn_readfirstlane(w);
  int c0 = wu*32;
  int l4 = (lane < 54) ? lane : 53;

  f32x4 acc[16];
  #pragma unroll
  for (int k=0;k<16;k++) acc[k] = (f32x4){0,0,0,0};

  const float* f2base = feat2 + (size_t)b*NCC*NHW + px0 + l4*4;
  const float* kfb = kflat + (size_t)b*4096;
  #pragma unroll 4
  for (int c = c0; c < c0+32; ++c){
    f32x4 r = *(const f32x4*)(f2base + (size_t)c*NHW);
    f32x16 kf = *(const f32x16*)(kfb + c*16);
    #pragma unroll
    for (int k=0;k<16;k++){
      f32x4 kv = {kf[k], kf[k], kf[k], kf[k]};
      acc[k] = __builtin_elementwise_fma(r, kv, acc[k]);
    }
  }

  if (w >= 4){
    #pragma unroll
    for (int k=0;k<16;k++)
      *(f32x4*)&par[w-4][k][l4*4] = acc[k];
  }
  __syncthreads();
  if (w < 4){
    #pragma unroll
    for (int k=0;k<16;k++){
      f32x4 tmp = *(const f32x4*)&par[w][k][l4*4];
      *(f32x4*)&par[w][k][l4*4] = tmp + acc[k];
    }
  }
  __syncthreads();
  int k = (w<<1) | (lane>>5);
  int j0 = lane & 31;
  float se_r = 0.0f;
  float* cp = corr + (size_t)b*NK*NHW + (size_t)k*NHW + px0;
  for (int jj=j0; jj<54; jj+=32){
    f32x4 s = *(const f32x4*)&par[0][k][jj*4];
    s += *(const f32x4*)&par[1][k][jj*4];
    s += *(const f32x4*)&par[2][k][jj*4];
    s += *(const f32x4*)&par[3][k][jj*4];
    *(f32x4*)(cp + jj*4) = s;
    se_r += (s.x+s.y) + (s.z+s.w);
  }
  #pragma unroll
  for (int off=16; off>0; off>>=1) se_r += __shfl_down(se_r, off, 32);
  if (j0 == 0)
    partial_se[(size_t)blk*16 + k] = se_r;
}

// ---- K3: SE gate + bf16 hi/lo theta/phi + V^T(bf16, ones col) -----------
__global__ __launch_bounds__(64) void k_tpg(const float* __restrict__ corr,
    const float* __restrict__ partial_se,
    const float* __restrict__ w1, const float* __restrict__ w2,
    const float* __restrict__ tw, const float* __restrict__ tb,
    const float* __restrict__ pw, const float* __restrict__ pb,
    const float* __restrict__ gw, const float* __restrict__ gb,
    float* __restrict__ sscale,
    unsigned short* __restrict__ thetaX, unsigned short* __restrict__ phiX,
    unsigned short* __restrict__ gT){
  int blk = blockIdx.x;          // b*21 + ch
  int b = blk/21, ch = blk - b*21;
  int t = threadIdx.x;
  __shared__ float Wt[128], Wp[128], Wg[128], Bz[24], Ss[16], sS[16], sR[4];
  for (int i=t; i<128; i+=64){ Wt[i]=tw[i]; Wp[i]=pw[i]; Wg[i]=gw[i]; }
  if (t < 8){ Bz[t]=tb[t]; Bz[8+t]=pb[t]; Bz[16+t]=gb[t]; }
  if (t < 16){
    float a = 0.f;
    #pragma unroll
    for (int c2=0; c2<6; c2++) a += partial_se[(size_t)(b*6+c2)*16 + t];
    sS[t] = a * (1.0f/1296.0f);
  }
  __syncthreads();
  if (t < 4){
    float a=0.f;
    #pragma unroll
    for (int k=0;k<16;k++) a += sS[k]*w1[t*16+k];
    sR[t] = fmaxf(a, 0.f);
  }
  __syncthreads();
  if (t < 16){
    float a=0.f;
    #pragma unroll
    for (int j=0;j<4;j++) a += sR[j]*w2[t*4+j];
    float gsc = 1.0f/(1.0f+__expf(-a));
    Ss[t] = gsc;
    if (ch == 0) sscale[b*16+t] = gsc;
  }
  __syncthreads();
  int n = ch*64 + t;
  if (n >= NHW) return;
  float x[16];
  const float* cp = corr + (size_t)b*NK*NHW + n;
  #pragma unroll
  for (int c=0;c<16;c++) x[c] = cp[(size_t)c*NHW] * Ss[c];
  float th[8], ph[8], gg[8];
  #pragma unroll
  for (int o=0;o<8;o++){
    float a=Bz[o], p2=Bz[8+o], gq=Bz[16+o];
    #pragma unroll
    for (int c=0;c<16;c++){
      a  += Wt[o*16+c]*x[c];
      p2 += Wp[o*16+c]*x[c];
      gq += Wg[o*16+c]*x[c];
    }
    th[o]=a*LOG2E; ph[o]=p2; gg[o]=gq;   // theta pre-scaled: exp2 domain
  }
  unsigned short tH[8], tL[8], pH[8], pL[8];
  #pragma unroll
  for (int o=0;o<8;o++){
    unsigned short hh = bf16rn(th[o]);
    tH[o] = hh; tL[o] = bf16rn(th[o] - bf16tof(hh));
    unsigned short ph2 = bf16rn(ph[o]);
    pH[o] = ph2; pL[o] = bf16rn(ph[o] - bf16tof(ph2));
  }
  // row layout (16 ushorts): [H0-3 | L0-3 | H4-7 | L4-7]
  {
    u16x8* tp = (u16x8*)(thetaX + ((size_t)b*NPAD + n)*16);
    tp[0] = (u16x8){tH[0],tH[1],tH[2],tH[3], tL[0],tL[1],tL[2],tL[3]};
    tp[1] = (u16x8){tH[4],tH[5],tH[6],tH[7], tL[4],tL[5],tL[6],tL[7]};
    u16x8* pp = (u16x8*)(phiX + ((size_t)b*NPAD + n)*16);
    pp[0] = (u16x8){pH[0],pH[1],pH[2],pH[3], pL[0],pL[1],pL[2],pL[3]};
    pp[1] = (u16x8){pH[4],pH[5],pH[6],pH[7], pL[4],pL[5],pL[6],pL[7]};
  }
  #pragma unroll
  for (int o=0;o<8;o++)
    gT[((size_t)b*16 + o)*NPAD + n] = bf16rn(gg[o]);
  gT[((size_t)b*16 + 8)*NPAD + n] = 0x3F80;  // ones column -> l
}

// ---- K4: MFMA flash attention (swapped S^T, 2-pass, hi/lo bf16) ---------
__global__ __launch_bounds__(128) void k_attn(
    const unsigned short* __restrict__ thetaX, const unsigned short* __restrict__ phiX,
    const unsigned short* __restrict__ gT,
    const float* __restrict__ corr, const float* __restrict__ sscale,
    const float* __restrict__ Ww, const float* __restrict__ Wb,
    float* __restrict__ out){
  int blk = blockIdx.x;
  int b = blk / 41, qb = blk - b*41;
  int t = threadIdx.x, w = t >> 6, lane = t & 63;
  int h = lane >> 5, r31 = lane & 31;
  __shared__ float smm[2][32];
  __shared__ float sY[16][64];
  __shared__ float yl[32][12];

  const unsigned short* thx = thetaX + (size_t)b*NPAD*16;
  const unsigned short* phx = phiX   + (size_t)b*NPAD*16;

  // B-frags (theta for query q=r31): lane h supplies k=h*4+j
  s16x4 Bh, Bl;
  {
    u16x8 tv = *(const u16x8*)(thx + ((size_t)(qb*32 + r31))*16 + h*8);
    Bh = (s16x4){(short)tv[0],(short)tv[1],(short)tv[2],(short)tv[3]};
    Bl = (s16x4){(short)tv[4],(short)tv[5],(short)tv[6],(short)tv[7]};
  }

  int kt0 = w ? 21 : 0;
  int ktN = w ? 41 : 21;

  // ---- pass 1: approx scores (phi_hi * theta_hi), true row max ----------
  float m = -1e30f;
  for (int kt = kt0; kt < ktN; ++kt){
    u16x8 av = *(const u16x8*)(phx + ((size_t)(kt*32 + r31))*16 + h*8);
    s16x4 Ah = (s16x4){(short)av[0],(short)av[1],(short)av[2],(short)av[3]};
    f32x16 S = __builtin_amdgcn_mfma_f32_32x32x8bf16_1k(Ah, Bh, (f32x16)(0.0f), 0, 0, 0);
    if (kt != 40){
      #pragma unroll
      for (int r=0;r<16;r++) m = fmaxf(m, S[r]);
    } else {
      #pragma unroll
      for (int r=0;r<8;r++) m = fmaxf(m, S[r]);
    }
  }
  m = fmaxf(m, __shfl_xor(m, 32));
  if (h == 0) smm[w][r31] = m;
  __syncthreads();
  m = fmaxf(smm[0][r31], smm[1][r31]);   // global max for query r31

  // ---- pass 2: exact scores, exp2, PV via MFMA --------------------------
  f32x16 Y = (f32x16)(0.0f);
  int colc = (r31 < 9) ? r31 : 0;        // clamp V column (cols >8 unused)
  const unsigned short* gb2 = gT + ((size_t)b*16 + colc)*NPAD;

  for (int kt = kt0; kt < ktN; ++kt){
    u16x8 av = *(const u16x8*)(phx + ((size_t)(kt*32 + r31))*16 + h*8);
    s16x4 Ah = (s16x4){(short)av[0],(short)av[1],(short)av[2],(short)av[3]};
    s16x4 Al = (s16x4){(short)av[4],(short)av[5],(short)av[6],(short)av[7]};
    f32x16 S = __builtin_amdgcn_mfma_f32_32x32x8bf16_1k(Ah, Bl, (f32x16)(0.0f), 0, 0, 0);
    S = __builtin_amdgcn_mfma_f32_32x32x8bf16_1k(Al, Bh, S, 0, 0, 0);
    S = __builtin_amdgcn_mfma_f32_32x32x8bf16_1k(Ah, Bh, S, 0, 0, 0);
    if (kt == 40){
      #pragma unroll
      for (int r=8;r<16;r++) S[r] = -1e30f;   // mask pad keys 1296..1311
    }
    float p[16];
    #pragma unroll
    for (int r=0;r<16;r++) p[r] = __builtin_amdgcn_exp2f(S[r] - m);
    unsigned int c[8];
    #pragma unroll
    for (int i=0;i<8;i++){
      unsigned int cc;
      asm("v_cvt_pk_bf16_f32 %0, %1, %2" : "=v"(cc) : "v"(p[2*i]), "v"(p[2*i+1]));
      c[i] = cc;
    }
    #pragma unroll
    for (int mf=0; mf<4; ++mf){
      s16x4 Ap = __builtin_bit_cast(s16x4, (u32x2){c[2*mf], c[2*mf+1]});
      u32x2 vv = *(const u32x2*)(gb2 + kt*32 + mf*8 + h*4);
      s16x4 Vb = __builtin_bit_cast(s16x4, vv);
      Y = __builtin_amdgcn_mfma_f32_32x32x8bf16_1k(Ap, Vb, Y, 0, 0, 0);
    }
  }

  // ---- merge across the 2 waves, then layout y per query in LDS ---------
  if (w == 1){
    #pragma unroll
    for (int r=0;r<16;r++) sY[r][lane] = Y[r];
  }
  __syncthreads();
  if (w == 0){
    #pragma unroll
    for (int r=0;r<16;r++) Y[r] += sY[r][lane];
    if (r31 < 9){
      #pragma unroll
      for (int r=0;r<16;r++){
        int q = (r&3) + 8*(r>>2) + 4*h;
        yl[q][r31] = Y[r];
      }
    }
  }
  __syncthreads();

  // ---- epilogue: W-proj + residual; 128 threads = 32 q x 4 c-groups -----
  int q = t & 31, cg = t >> 5;
  int n = qb*32 + q;
  if (n < NHW){
    float il = 1.0f / yl[q][8];
    float yv[8];
    #pragma unroll
    for (int o=0;o<8;o++) yv[o] = yl[q][o] * il;
    const float* cp = corr + (size_t)b*NK*NHW + n;
    const float* ss = sscale + b*16;
    float* op = out + (size_t)b*NK*NHW + n;
    #pragma unroll
    for (int i=0;i<4;i++){
      int c2 = cg*4 + i;
      float z = Wb[c2];
      #pragma unroll
      for (int o=0;o<8;o++) z += Ww[c2*8+o]*yv[o];
      op[(size_t)c2*NHW] = z + cp[(size_t)c2*NHW]*ss[c2];
    }
  }
}

extern "C" void kernel_launch(void* const* d_in, const int* in_sizes, int n_in,
                              void* d_out, int out_size, void* d_ws, size_t ws_size,
                              hipStream_t stream){
  const float* feat1 = (const float*)d_in[0];
  const float* feat2 = (const float*)d_in[1];
  const float* bb1   = (const float*)d_in[2];
  const float* se_w1 = (const float*)d_in[3];
  const float* se_w2 = (const float*)d_in[4];
  const float* tw    = (const float*)d_in[5];
  const float* tb    = (const float*)d_in[6];
  const float* pw    = (const float*)d_in[7];
  const float* pb    = (const float*)d_in[8];
  const float* gw    = (const float*)d_in[9];
  const float* gb    = (const float*)d_in[10];
  const float* Ww    = (const float*)d_in[11];
  const float* Wb    = (const float*)d_in[12];
  float* out = (float*)d_out;

  float* ws = (float*)d_ws;
  float* kflat      = ws;                                // 64*256*16       = 262144 f
  float* corr       = kflat + 64*256*16;                 // 64*16*1296      = 1327104 f
  float* partial_se = corr + (size_t)64*16*1296;         // 64*6*16         = 6144 f
  float* sscale     = partial_se + 64*6*16;              // 64*16           = 1024 f
  unsigned short* thetaX = (unsigned short*)(sscale + 64*16);   // 64*1312*16 u16
  unsigned short* phiX   = thetaX + (size_t)64*NPAD*16;         // 64*1312*16 u16
  unsigned short* gT     = phiX   + (size_t)64*NPAD*16;         // 64*16*1312 u16

  hipLaunchKernelGGL(k_prpool, dim3(64*64), dim3(256), 0, stream, feat1, bb1, kflat);
  hipLaunchKernelGGL(k_corr, dim3(64*6), dim3(512), 0, stream, feat2, kflat, corr, partial_se);
  hipLaunchKernelGGL(k_tpg, dim3(64*21), dim3(64), 0, stream, corr, partial_se,
                     se_w1, se_w2, tw, tb, pw, pb, gw, gb, sscale, thetaX, phiX, gT);
  hipLaunchKernelGGL(k_attn, dim3(64*41), dim3(128), 0, stream,
                     thetaX, phiX, gT, corr, sscale, Ww, Wb, out);
}

// Round 10
// 122.879 us; speedup vs baseline: 2.8648x; 1.0013x over previous
//
#include <hip/hip_runtime.h>
#include <cmath>

#define NB 64
#define NCC 256
#define NH 36
#define NW 36
#define NHW 1296
#define NK 16
#define NI 8
#define SC (1.0f/16.0f)
#define LOG2E 1.4426950408889634f
#define NPAD 1312   // 41*32

typedef __attribute__((ext_vector_type(16))) float f32x16;
typedef __attribute__((ext_vector_type(4)))  float f32x4;
typedef __attribute__((ext_vector_type(4)))  short s16x4;
typedef __attribute__((ext_vector_type(8)))  unsigned short u16x8;
typedef __attribute__((ext_vector_type(2)))  unsigned int u32x2;

__device__ __forceinline__ float hatc(float t){
  t = fminf(fmaxf(t, -1.0f), 1.0f);
  float a = 1.0f + t, bq = 1.0f - t;
  return (t < 0.0f) ? 0.5f*a*a : 1.0f - 0.5f*bq*bq;
}

__device__ __forceinline__ unsigned short bf16rn(float f){
  unsigned int u = __builtin_bit_cast(unsigned int, f);
  return (unsigned short)((u + 0x7FFFu + ((u >> 16) & 1u)) >> 16);
}
__device__ __forceinline__ float bf16tof(unsigned short h){
  unsigned int u = ((unsigned int)h) << 16;
  return __builtin_bit_cast(float, u);
}

// ---- K1: PrRoI pooling; 1 wave per (b,c); float4 feature loads ----------
__global__ __launch_bounds__(256) void k_prpool(const float* __restrict__ feat1,
    const float* __restrict__ bb1, float* __restrict__ kflat){
  int blk = blockIdx.x;          // b*64 + cg
  int b = blk >> 6, cg = blk & 63;
  int t = threadIdx.x, w = t >> 6, lane = t & 63;
  int c = cg*4 + w;
  __shared__ float4 wY4[36];
  __shared__ float  wXp[36*5];
  float bx = bb1[b*4+0], by = bb1[b*4+1], bwv = bb1[b*4+2], bhv = bb1[b*4+3];
  float x1 = bx*SC, y1 = by*SC;
  float binw = bwv*SC*0.25f, binh = bhv*SC*0.25f;
  if (t < 36){
    float fi = (float)t;
    float4 r;
    r.x = hatc(y1 + 1.0f*binh - fi) - hatc(y1 + 0.0f*binh - fi);
    r.y = hatc(y1 + 2.0f*binh - fi) - hatc(y1 + 1.0f*binh - fi);
    r.z = hatc(y1 + 3.0f*binh - fi) - hatc(y1 + 2.0f*binh - fi);
    r.w = hatc(y1 + 4.0f*binh - fi) - hatc(y1 + 3.0f*binh - fi);
    wY4[t] = r;
  } else if (t < 72){
    int i = t - 36;
    float fi = (float)i;
    wXp[i*5+0] = hatc(x1 + 1.0f*binw - fi) - hatc(x1 + 0.0f*binw - fi);
    wXp[i*5+1] = hatc(x1 + 2.0f*binw - fi) - hatc(x1 + 1.0f*binw - fi);
    wXp[i*5+2] = hatc(x1 + 3.0f*binw - fi) - hatc(x1 + 2.0f*binw - fi);
    wXp[i*5+3] = hatc(x1 + 4.0f*binw - fi) - hatc(x1 + 3.0f*binw - fi);
  }
  __syncthreads();
  f32x4 acc4[4];
  #pragma unroll
  for (int p=0;p<4;p++) acc4[p] = (f32x4){0,0,0,0};
  const float4* fp4 = (const float4*)(feat1 + ((size_t)(b*256+c))*NHW);

  auto body = [&](float4 v, int px){
    #pragma unroll
    for (int j=0;j<4;j++){
      int p = px + j;
      int h = p/36, x = p - h*36;
      float vj = (j==0)?v.x:(j==1)?v.y:(j==2)?v.z:v.w;
      float4 wy = wY4[h];
      f32x4 wxv = {wXp[x*5+0], wXp[x*5+1], wXp[x*5+2], wXp[x*5+3]};
      f32x4 a0 = {vj*wy.x, vj*wy.x, vj*wy.x, vj*wy.x};
      f32x4 a1 = {vj*wy.y, vj*wy.y, vj*wy.y, vj*wy.y};
      f32x4 a2 = {vj*wy.z, vj*wy.z, vj*wy.z, vj*wy.z};
      f32x4 a3 = {vj*wy.w, vj*wy.w, vj*wy.w, vj*wy.w};
      acc4[0] = __builtin_elementwise_fma(a0, wxv, acc4[0]);
      acc4[1] = __builtin_elementwise_fma(a1, wxv, acc4[1]);
      acc4[2] = __builtin_elementwise_fma(a2, wxv, acc4[2]);
      acc4[3] = __builtin_elementwise_fma(a3, wxv, acc4[3]);
    }
  };

  #pragma unroll
  for (int i=0;i<5;i++){
    int f4i = i*64 + lane;
    float4 v = fp4[f4i];
    body(v, f4i*4);
  }
  if (lane < 4){
    int f4i = 320 + lane;
    float4 v = fp4[f4i];
    body(v, f4i*4);
  }
  float accf[16];
  #pragma unroll
  for (int p=0;p<4;p++){
    accf[p*4+0]=acc4[p].x; accf[p*4+1]=acc4[p].y;
    accf[p*4+2]=acc4[p].z; accf[p*4+3]=acc4[p].w;
  }
  #pragma unroll
  for (int k=0;k<16;k++){
    float a = accf[k];
    #pragma unroll
    for (int off=32; off>0; off>>=1) a += __shfl_down(a, off);
    accf[k] = a;
  }
  if (lane == 0){
    float area = binw*binh;
    float ia = (area > 0.0f) ? 1.0f/fmaxf(area,1e-12f) : 0.0f;
    float4* kp = (float4*)(kflat + ((size_t)(b*256+c))*16);
    kp[0] = make_float4(accf[0]*ia, accf[1]*ia, accf[2]*ia, accf[3]*ia);
    kp[1] = make_float4(accf[4]*ia, accf[5]*ia, accf[6]*ia, accf[7]*ia);
    kp[2] = make_float4(accf[8]*ia, accf[9]*ia, accf[10]*ia, accf[11]*ia);
    kp[3] = make_float4(accf[12]*ia, accf[13]*ia, accf[14]*ia, accf[15]*ia);
  }
}

// ---- K2: pixel corr; float4 pixel loads, 8-way channel split ------------
__global__ __launch_bounds__(512) void k_corr(const float* __restrict__ feat2,
    const float* __restrict__ kflat, float* __restrict__ corr,
    float* __restrict__ partial_se){
  int blk = blockIdx.x;          // b*6 + ch
  int b = blk / 6, ch = blk - b*6;
  int t = threadIdx.x, w = t >> 6, lane = t & 63;
  int px0 = ch*216;
  __shared__ float par[4][16][216];

  int wu = __builtin_amdgcn_readfirstlane(w);
  int c0 = wu*32;
  int l4 = (lane < 54) ? lane : 53;

  f32x4 acc[16];
  #pragma unroll
  for (int k=0;k<16;k++) acc[k] = (f32x4){0,0,0,0};

  const float* f2base = feat2 + (size_t)b*NCC*NHW + px0 + l4*4;
  const float* kfb = kflat + (size_t)b*4096;
  #pragma unroll 4
  for (int c = c0; c < c0+32; ++c){
    f32x4 r = *(const f32x4*)(f2base + (size_t)c*NHW);
    f32x16 kf = *(const f32x16*)(kfb + c*16);
    #pragma unroll
    for (int k=0;k<16;k++){
      f32x4 kv = {kf[k], kf[k], kf[k], kf[k]};
      acc[k] = __builtin_elementwise_fma(r, kv, acc[k]);
    }
  }

  if (w >= 4){
    #pragma unroll
    for (int k=0;k<16;k++)
      *(f32x4*)&par[w-4][k][l4*4] = acc[k];
  }
  __syncthreads();
  if (w < 4){
    #pragma unroll
    for (int k=0;k<16;k++){
      f32x4 tmp = *(const f32x4*)&par[w][k][l4*4];
      *(f32x4*)&par[w][k][l4*4] = tmp + acc[k];
    }
  }
  __syncthreads();
  int k = (w<<1) | (lane>>5);
  int j0 = lane & 31;
  float se_r = 0.0f;
  float* cp = corr + (size_t)b*NK*NHW + (size_t)k*NHW + px0;
  for (int jj=j0; jj<54; jj+=32){
    f32x4 s = *(const f32x4*)&par[0][k][jj*4];
    s += *(const f32x4*)&par[1][k][jj*4];
    s += *(const f32x4*)&par[2][k][jj*4];
    s += *(const f32x4*)&par[3][k][jj*4];
    *(f32x4*)(cp + jj*4) = s;
    se_r += (s.x+s.y) + (s.z+s.w);
  }
  #pragma unroll
  for (int off=16; off>0; off>>=1) se_r += __shfl_down(se_r, off, 32);
  if (j0 == 0)
    partial_se[(size_t)blk*16 + k] = se_r;
}

// ---- K3: SE gate + bf16 hi/lo theta/phi + V^T(bf16, ones col) -----------
__global__ __launch_bounds__(64) void k_tpg(const float* __restrict__ corr,
    const float* __restrict__ partial_se,
    const float* __restrict__ w1, const float* __restrict__ w2,
    const float* __restrict__ tw, const float* __restrict__ tb,
    const float* __restrict__ pw, const float* __restrict__ pb,
    const float* __restrict__ gw, const float* __restrict__ gb,
    float* __restrict__ sscale,
    unsigned short* __restrict__ thetaX, unsigned short* __restrict__ phiX,
    unsigned short* __restrict__ gT){
  int blk = blockIdx.x;          // b*21 + ch
  int b = blk/21, ch = blk - b*21;
  int t = threadIdx.x;
  __shared__ float Wt[128], Wp[128], Wg[128], Bz[24], Ss[16], sS[16], sR[4];
  for (int i=t; i<128; i+=64){ Wt[i]=tw[i]; Wp[i]=pw[i]; Wg[i]=gw[i]; }
  if (t < 8){ Bz[t]=tb[t]; Bz[8+t]=pb[t]; Bz[16+t]=gb[t]; }
  if (t < 16){
    float a = 0.f;
    #pragma unroll
    for (int c2=0; c2<6; c2++) a += partial_se[(size_t)(b*6+c2)*16 + t];
    sS[t] = a * (1.0f/1296.0f);
  }
  __syncthreads();
  if (t < 4){
    float a=0.f;
    #pragma unroll
    for (int k=0;k<16;k++) a += sS[k]*w1[t*16+k];
    sR[t] = fmaxf(a, 0.f);
  }
  __syncthreads();
  if (t < 16){
    float a=0.f;
    #pragma unroll
    for (int j=0;j<4;j++) a += sR[j]*w2[t*4+j];
    float gsc = 1.0f/(1.0f+__expf(-a));
    Ss[t] = gsc;
    if (ch == 0) sscale[b*16+t] = gsc;
  }
  __syncthreads();
  int n = ch*64 + t;
  if (n >= NHW) return;
  float x[16];
  const float* cp = corr + (size_t)b*NK*NHW + n;
  #pragma unroll
  for (int c=0;c<16;c++) x[c] = cp[(size_t)c*NHW] * Ss[c];
  float th[8], ph[8], gg[8];
  #pragma unroll
  for (int o=0;o<8;o++){
    float a=Bz[o], p2=Bz[8+o], gq=Bz[16+o];
    #pragma unroll
    for (int c=0;c<16;c++){
      a  += Wt[o*16+c]*x[c];
      p2 += Wp[o*16+c]*x[c];
      gq += Wg[o*16+c]*x[c];
    }
    th[o]=a*LOG2E; ph[o]=p2; gg[o]=gq;   // theta pre-scaled: exp2 domain
  }
  unsigned short tH[8], tL[8], pH[8], pL[8];
  #pragma unroll
  for (int o=0;o<8;o++){
    unsigned short hh = bf16rn(th[o]);
    tH[o] = hh; tL[o] = bf16rn(th[o] - bf16tof(hh));
    unsigned short ph2 = bf16rn(ph[o]);
    pH[o] = ph2; pL[o] = bf16rn(ph[o] - bf16tof(ph2));
  }
  // row layout (16 ushorts): [H0-3 | L0-3 | H4-7 | L4-7]
  {
    u16x8* tp = (u16x8*)(thetaX + ((size_t)b*NPAD + n)*16);
    tp[0] = (u16x8){tH[0],tH[1],tH[2],tH[3], tL[0],tL[1],tL[2],tL[3]};
    tp[1] = (u16x8){tH[4],tH[5],tH[6],tH[7], tL[4],tL[5],tL[6],tL[7]};
    u16x8* pp = (u16x8*)(phiX + ((size_t)b*NPAD + n)*16);
    pp[0] = (u16x8){pH[0],pH[1],pH[2],pH[3], pL[0],pL[1],pL[2],pL[3]};
    pp[1] = (u16x8){pH[4],pH[5],pH[6],pH[7], pL[4],pL[5],pL[6],pL[7]};
  }
  #pragma unroll
  for (int o=0;o<8;o++)
    gT[((size_t)b*16 + o)*NPAD + n] = bf16rn(gg[o]);
  gT[((size_t)b*16 + 8)*NPAD + n] = 0x3F80;  // ones column -> l
}

// ---- K4: MFMA flash attention (swapped S^T, 2-pass, hi/lo bf16) ---------
__global__ __launch_bounds__(128) void k_attn(
    const unsigned short* __restrict__ thetaX, const unsigned short* __restrict__ phiX,
    const unsigned short* __restrict__ gT,
    const float* __restrict__ corr, const float* __restrict__ sscale,
    const float* __restrict__ Ww, const float* __restrict__ Wb,
    float* __restrict__ out){
  int blk = blockIdx.x;
  int b = blk / 41, qb = blk - b*41;
  int t = threadIdx.x, w = t >> 6, lane = t & 63;
  int h = lane >> 5, r31 = lane & 31;
  __shared__ float smm[2][32];
  __shared__ float sY[16][64];
  __shared__ float yl[32][12];

  const unsigned short* thx = thetaX + (size_t)b*NPAD*16;
  const unsigned short* phx = phiX   + (size_t)b*NPAD*16;

  // B-frags (theta for query q=r31): lane h supplies k=h*4+j
  s16x4 Bh, Bl;
  {
    u16x8 tv = *(const u16x8*)(thx + ((size_t)(qb*32 + r31))*16 + h*8);
    Bh = (s16x4){(short)tv[0],(short)tv[1],(short)tv[2],(short)tv[3]};
    Bl = (s16x4){(short)tv[4],(short)tv[5],(short)tv[6],(short)tv[7]};
  }

  int kt0 = w ? 21 : 0;
  int ktN = w ? 41 : 21;

  // ---- pass 1: approx scores (phi_hi * theta_hi), true row max ----------
  float m = -1e30f;
  for (int kt = kt0; kt < ktN; ++kt){
    u16x8 av = *(const u16x8*)(phx + ((size_t)(kt*32 + r31))*16 + h*8);
    s16x4 Ah = (s16x4){(short)av[0],(short)av[1],(short)av[2],(short)av[3]};
    f32x16 S = __builtin_amdgcn_mfma_f32_32x32x8bf16_1k(Ah, Bh, (f32x16)(0.0f), 0, 0, 0);
    if (kt != 40){
      #pragma unroll
      for (int r=0;r<16;r++) m = fmaxf(m, S[r]);
    } else {
      #pragma unroll
      for (int r=0;r<8;r++) m = fmaxf(m, S[r]);
    }
  }
  m = fmaxf(m, __shfl_xor(m, 32));
  if (h == 0) smm[w][r31] = m;
  __syncthreads();
  m = fmaxf(smm[0][r31], smm[1][r31]);   // global max for query r31

  // ---- pass 2: exact scores, exp2, PV via MFMA --------------------------
  f32x16 Y = (f32x16)(0.0f);
  int colc = (r31 < 9) ? r31 : 0;        // clamp V column (cols >8 unused)
  const unsigned short* gb2 = gT + ((size_t)b*16 + colc)*NPAD;

  for (int kt = kt0; kt < ktN; ++kt){
    u16x8 av = *(const u16x8*)(phx + ((size_t)(kt*32 + r31))*16 + h*8);
    s16x4 Ah = (s16x4){(short)av[0],(short)av[1],(short)av[2],(short)av[3]};
    s16x4 Al = (s16x4){(short)av[4],(short)av[5],(short)av[6],(short)av[7]};
    f32x16 S = __builtin_amdgcn_mfma_f32_32x32x8bf16_1k(Ah, Bl, (f32x16)(0.0f), 0, 0, 0);
    S = __builtin_amdgcn_mfma_f32_32x32x8bf16_1k(Al, Bh, S, 0, 0, 0);
    S = __builtin_amdgcn_mfma_f32_32x32x8bf16_1k(Ah, Bh, S, 0, 0, 0);
    if (kt == 40){
      #pragma unroll
      for (int r=8;r<16;r++) S[r] = -1e30f;   // mask pad keys 1296..1311
    }
    float p[16];
    #pragma unroll
    for (int r=0;r<16;r++) p[r] = __builtin_amdgcn_exp2f(S[r] - m);
    unsigned int c[8];
    #pragma unroll
    for (int i=0;i<8;i++){
      unsigned int cc;
      asm("v_cvt_pk_bf16_f32 %0, %1, %2" : "=v"(cc) : "v"(p[2*i]), "v"(p[2*i+1]));
      c[i] = cc;
    }
    #pragma unroll
    for (int mf=0; mf<4; ++mf){
      s16x4 Ap = __builtin_bit_cast(s16x4, (u32x2){c[2*mf], c[2*mf+1]});
      u32x2 vv = *(const u32x2*)(gb2 + kt*32 + mf*8 + h*4);
      s16x4 Vb = __builtin_bit_cast(s16x4, vv);
      Y = __builtin_amdgcn_mfma_f32_32x32x8bf16_1k(Ap, Vb, Y, 0, 0, 0);
    }
  }

  // ---- merge across the 2 waves, then layout y per query in LDS ---------
  if (w == 1){
    #pragma unroll
    for (int r=0;r<16;r++) sY[r][lane] = Y[r];
  }
  __syncthreads();
  if (w == 0){
    #pragma unroll
    for (int r=0;r<16;r++) Y[r] += sY[r][lane];
    if (r31 < 9){
      #pragma unroll
      for (int r=0;r<16;r++){
        int q = (r&3) + 8*(r>>2) + 4*h;
        yl[q][r31] = Y[r];
      }
    }
  }
  __syncthreads();

  // ---- epilogue: W-proj + residual; 128 threads = 32 q x 4 c-groups -----
  int q = t & 31, cg = t >> 5;
  int n = qb*32 + q;
  if (n < NHW){
    float il = 1.0f / yl[q][8];
    float yv[8];
    #pragma unroll
    for (int o=0;o<8;o++) yv[o] = yl[q][o] * il;
    const float* cp = corr + (size_t)b*NK*NHW + n;
    const float* ss = sscale + b*16;
    float* op = out + (size_t)b*NK*NHW + n;
    #pragma unroll
    for (int i=0;i<4;i++){
      int c2 = cg*4 + i;
      float z = Wb[c2];
      #pragma unroll
      for (int o=0;o<8;o++) z += Ww[c2*8+o]*yv[o];
      op[(size_t)c2*NHW] = z + cp[(size_t)c2*NHW]*ss[c2];
    }
  }
}

extern "C" void kernel_launch(void* const* d_in, const int* in_sizes, int n_in,
                              void* d_out, int out_size, void* d_ws, size_t ws_size,
                              hipStream_t stream){
  const float* feat1 = (const float*)d_in[0];
  const float* feat2 = (const float*)d_in[1];
  const float* bb1   = (const float*)d_in[2];
  const float* se_w1 = (const float*)d_in[3];
  const float* se_w2 = (const float*)d_in[4];
  const float* tw    = (const float*)d_in[5];
  const float* tb    = (const float*)d_in[6];
  const float* pw    = (const float*)d_in[7];
  const float* pb    = (const float*)d_in[8];
  const float* gw    = (const float*)d_in[9];
  const float* gb    = (const float*)d_in[10];
  const float* Ww    = (const float*)d_in[11];
  const float* Wb    = (const float*)d_in[12];
  float* out = (float*)d_out;

  float* ws = (float*)d_ws;
  float* kflat      = ws;                                // 64*256*16       = 262144 f
  float* corr       = kflat + 64*256*16;                 // 64*16*1296      = 1327104 f
  float* partial_se = corr + (size_t)64*16*1296;         // 64*6*16         = 6144 f
  float* sscale     = partial_se + 64*6*16;              // 64*16           = 1024 f
  unsigned short* thetaX = (unsigned short*)(sscale + 64*16);   // 64*1312*16 u16
  unsigned short* phiX   = thetaX + (size_t)64*NPAD*16;         // 64*1312*16 u16
  unsigned short* gT     = phiX   + (size_t)64*NPAD*16;         // 64*16*1312 u16

  hipLaunchKernelGGL(k_prpool, dim3(64*64), dim3(256), 0, stream, feat1, bb1, kflat);
  hipLaunchKernelGGL(k_corr, dim3(64*6), dim3(512), 0, stream, feat2, kflat, corr, partial_se);
  hipLaunchKernelGGL(k_tpg, dim3(64*21), dim3(64), 0, stream, corr, partial_se,
                     se_w1, se_w2, tw, tb, pw, pb, gw, gb, sscale, thetaX, phiX, gT);
  hipLaunchKernelGGL(k_attn, dim3(64*41), dim3(128), 0, stream,
                     thetaX, phiX, gT, corr, sscale, Ww, Wb, out);
}

// Round 11
// 108.337 us; speedup vs baseline: 3.2493x; 1.1342x over previous
//
#include <hip/hip_runtime.h>
#include <cmath>

#define NB 64
#define NCC 256
#define NH 36
#define NW 36
#define NHW 1296
#define NK 16
#define NI 8
#define SC (1.0f/16.0f)
#define LOG2E 1.4426950408889634f
#define NPAD 1312   // 41*32

typedef __attribute__((ext_vector_type(16))) float f32x16;
typedef __attribute__((ext_vector_type(4)))  float f32x4;
typedef __attribute__((ext_vector_type(4)))  short s16x4;
typedef __attribute__((ext_vector_type(8)))  unsigned short u16x8;
typedef __attribute__((ext_vector_type(2)))  unsigned int u32x2;

__device__ __forceinline__ float hatc(float t){
  t = fminf(fmaxf(t, -1.0f), 1.0f);
  float a = 1.0f + t, bq = 1.0f - t;
  return (t < 0.0f) ? 0.5f*a*a : 1.0f - 0.5f*bq*bq;
}

__device__ __forceinline__ unsigned short bf16rn(float f){
  unsigned int u = __builtin_bit_cast(unsigned int, f);
  return (unsigned short)((u + 0x7FFFu + ((u >> 16) & 1u)) >> 16);
}
__device__ __forceinline__ float bf16tof(unsigned short h){
  unsigned int u = ((unsigned int)h) << 16;
  return __builtin_bit_cast(float, u);
}

// ---- K1: PrRoI pooling; 1 wave per (b,c); float4 feature loads ----------
__global__ __launch_bounds__(256) void k_prpool(const float* __restrict__ feat1,
    const float* __restrict__ bb1, float* __restrict__ kflat){
  int blk = blockIdx.x;          // b*64 + cg
  int b = blk >> 6, cg = blk & 63;
  int t = threadIdx.x, w = t >> 6, lane = t & 63;
  int c = cg*4 + w;
  __shared__ float4 wY4[36];
  __shared__ float  wXp[36*5];
  float bx = bb1[b*4+0], by = bb1[b*4+1], bwv = bb1[b*4+2], bhv = bb1[b*4+3];
  float x1 = bx*SC, y1 = by*SC;
  float binw = bwv*SC*0.25f, binh = bhv*SC*0.25f;
  if (t < 36){
    float fi = (float)t;
    float4 r;
    r.x = hatc(y1 + 1.0f*binh - fi) - hatc(y1 + 0.0f*binh - fi);
    r.y = hatc(y1 + 2.0f*binh - fi) - hatc(y1 + 1.0f*binh - fi);
    r.z = hatc(y1 + 3.0f*binh - fi) - hatc(y1 + 2.0f*binh - fi);
    r.w = hatc(y1 + 4.0f*binh - fi) - hatc(y1 + 3.0f*binh - fi);
    wY4[t] = r;
  } else if (t < 72){
    int i = t - 36;
    float fi = (float)i;
    wXp[i*5+0] = hatc(x1 + 1.0f*binw - fi) - hatc(x1 + 0.0f*binw - fi);
    wXp[i*5+1] = hatc(x1 + 2.0f*binw - fi) - hatc(x1 + 1.0f*binw - fi);
    wXp[i*5+2] = hatc(x1 + 3.0f*binw - fi) - hatc(x1 + 2.0f*binw - fi);
    wXp[i*5+3] = hatc(x1 + 4.0f*binw - fi) - hatc(x1 + 3.0f*binw - fi);
  }
  __syncthreads();
  f32x4 acc4[4];
  #pragma unroll
  for (int p=0;p<4;p++) acc4[p] = (f32x4){0,0,0,0};
  const float4* fp4 = (const float4*)(feat1 + ((size_t)(b*256+c))*NHW);

  auto body = [&](float4 v, int px){
    #pragma unroll
    for (int j=0;j<4;j++){
      int p = px + j;
      int h = p/36, x = p - h*36;
      float vj = (j==0)?v.x:(j==1)?v.y:(j==2)?v.z:v.w;
      float4 wy = wY4[h];
      f32x4 wxv = {wXp[x*5+0], wXp[x*5+1], wXp[x*5+2], wXp[x*5+3]};
      f32x4 a0 = {vj*wy.x, vj*wy.x, vj*wy.x, vj*wy.x};
      f32x4 a1 = {vj*wy.y, vj*wy.y, vj*wy.y, vj*wy.y};
      f32x4 a2 = {vj*wy.z, vj*wy.z, vj*wy.z, vj*wy.z};
      f32x4 a3 = {vj*wy.w, vj*wy.w, vj*wy.w, vj*wy.w};
      acc4[0] = __builtin_elementwise_fma(a0, wxv, acc4[0]);
      acc4[1] = __builtin_elementwise_fma(a1, wxv, acc4[1]);
      acc4[2] = __builtin_elementwise_fma(a2, wxv, acc4[2]);
      acc4[3] = __builtin_elementwise_fma(a3, wxv, acc4[3]);
    }
  };

  #pragma unroll
  for (int i=0;i<5;i++){
    int f4i = i*64 + lane;
    float4 v = fp4[f4i];
    body(v, f4i*4);
  }
  if (lane < 4){
    int f4i = 320 + lane;
    float4 v = fp4[f4i];
    body(v, f4i*4);
  }
  float accf[16];
  #pragma unroll
  for (int p=0;p<4;p++){
    accf[p*4+0]=acc4[p].x; accf[p*4+1]=acc4[p].y;
    accf[p*4+2]=acc4[p].z; accf[p*4+3]=acc4[p].w;
  }
  #pragma unroll
  for (int k=0;k<16;k++){
    float a = accf[k];
    #pragma unroll
    for (int off=32; off>0; off>>=1) a += __shfl_down(a, off);
    accf[k] = a;
  }
  if (lane == 0){
    float area = binw*binh;
    float ia = (area > 0.0f) ? 1.0f/fmaxf(area,1e-12f) : 0.0f;
    float4* kp = (float4*)(kflat + ((size_t)(b*256+c))*16);
    kp[0] = make_float4(accf[0]*ia, accf[1]*ia, accf[2]*ia, accf[3]*ia);
    kp[1] = make_float4(accf[4]*ia, accf[5]*ia, accf[6]*ia, accf[7]*ia);
    kp[2] = make_float4(accf[8]*ia, accf[9]*ia, accf[10]*ia, accf[11]*ia);
    kp[3] = make_float4(accf[12]*ia, accf[13]*ia, accf[14]*ia, accf[15]*ia);
  }
}

// ---- K2: pixel corr; float4 pixel loads, 8-way channel split ------------
__global__ __launch_bounds__(512) void k_corr(const float* __restrict__ feat2,
    const float* __restrict__ kflat, float* __restrict__ corr,
    float* __restrict__ partial_se){
  int blk = blockIdx.x;          // b*6 + ch
  int b = blk / 6, ch = blk - b*6;
  int t = threadIdx.x, w = t >> 6, lane = t & 63;
  int px0 = ch*216;
  __shared__ float par[4][16][216];

  int wu = __builtin_amdgcn_readfirstlane(w);
  int c0 = wu*32;
  int l4 = (lane < 54) ? lane : 53;

  f32x4 acc[16];
  #pragma unroll
  for (int k=0;k<16;k++) acc[k] = (f32x4){0,0,0,0};

  const float* f2base = feat2 + (size_t)b*NCC*NHW + px0 + l4*4;
  const float* kfb = kflat + (size_t)b*4096;
  #pragma unroll 4
  for (int c = c0; c < c0+32; ++c){
    f32x4 r = *(const f32x4*)(f2base + (size_t)c*NHW);
    f32x16 kf = *(const f32x16*)(kfb + c*16);
    #pragma unroll
    for (int k=0;k<16;k++){
      f32x4 kv = {kf[k], kf[k], kf[k], kf[k]};
      acc[k] = __builtin_elementwise_fma(r, kv, acc[k]);
    }
  }

  if (w >= 4){
    #pragma unroll
    for (int k=0;k<16;k++)
      *(f32x4*)&par[w-4][k][l4*4] = acc[k];
  }
  __syncthreads();
  if (w < 4){
    #pragma unroll
    for (int k=0;k<16;k++){
      f32x4 tmp = *(const f32x4*)&par[w][k][l4*4];
      *(f32x4*)&par[w][k][l4*4] = tmp + acc[k];
    }
  }
  __syncthreads();
  int k = (w<<1) | (lane>>5);
  int j0 = lane & 31;
  float se_r = 0.0f;
  float* cp = corr + (size_t)b*NK*NHW + (size_t)k*NHW + px0;
  for (int jj=j0; jj<54; jj+=32){
    f32x4 s = *(const f32x4*)&par[0][k][jj*4];
    s += *(const f32x4*)&par[1][k][jj*4];
    s += *(const f32x4*)&par[2][k][jj*4];
    s += *(const f32x4*)&par[3][k][jj*4];
    *(f32x4*)(cp + jj*4) = s;
    se_r += (s.x+s.y) + (s.z+s.w);
  }
  #pragma unroll
  for (int off=16; off>0; off>>=1) se_r += __shfl_down(se_r, off, 32);
  if (j0 == 0)
    partial_se[(size_t)blk*16 + k] = se_r;
}

// ---- K3: SE gate + bf16 hi/lo theta/phi + V^T(bf16, ones col) -----------
__global__ __launch_bounds__(64) void k_tpg(const float* __restrict__ corr,
    const float* __restrict__ partial_se,
    const float* __restrict__ w1, const float* __restrict__ w2,
    const float* __restrict__ tw, const float* __restrict__ tb,
    const float* __restrict__ pw, const float* __restrict__ pb,
    const float* __restrict__ gw, const float* __restrict__ gb,
    float* __restrict__ sscale,
    unsigned short* __restrict__ thetaX, unsigned short* __restrict__ phiX,
    unsigned short* __restrict__ gT){
  int blk = blockIdx.x;          // b*21 + ch
  int b = blk/21, ch = blk - b*21;
  int t = threadIdx.x;
  __shared__ float Wt[128], Wp[128], Wg[128], Bz[24], Ss[16], sS[16], sR[4];
  for (int i=t; i<128; i+=64){ Wt[i]=tw[i]; Wp[i]=pw[i]; Wg[i]=gw[i]; }
  if (t < 8){ Bz[t]=tb[t]; Bz[8+t]=pb[t]; Bz[16+t]=gb[t]; }
  if (t < 16){
    float a = 0.f;
    #pragma unroll
    for (int c2=0; c2<6; c2++) a += partial_se[(size_t)(b*6+c2)*16 + t];
    sS[t] = a * (1.0f/1296.0f);
  }
  __syncthreads();
  if (t < 4){
    float a=0.f;
    #pragma unroll
    for (int k=0;k<16;k++) a += sS[k]*w1[t*16+k];
    sR[t] = fmaxf(a, 0.f);
  }
  __syncthreads();
  if (t < 16){
    float a=0.f;
    #pragma unroll
    for (int j=0;j<4;j++) a += sR[j]*w2[t*4+j];
    float gsc = 1.0f/(1.0f+__expf(-a));
    Ss[t] = gsc;
    if (ch == 0) sscale[b*16+t] = gsc;
  }
  __syncthreads();
  int n = ch*64 + t;
  if (n >= NHW) return;
  float x[16];
  const float* cp = corr + (size_t)b*NK*NHW + n;
  #pragma unroll
  for (int c=0;c<16;c++) x[c] = cp[(size_t)c*NHW] * Ss[c];
  float th[8], ph[8], gg[8];
  #pragma unroll
  for (int o=0;o<8;o++){
    float a=Bz[o], p2=Bz[8+o], gq=Bz[16+o];
    #pragma unroll
    for (int c=0;c<16;c++){
      a  += Wt[o*16+c]*x[c];
      p2 += Wp[o*16+c]*x[c];
      gq += Wg[o*16+c]*x[c];
    }
    th[o]=a*LOG2E; ph[o]=p2; gg[o]=gq;   // theta pre-scaled: exp2 domain
  }
  unsigned short tH[8], tL[8], pH[8], pL[8];
  #pragma unroll
  for (int o=0;o<8;o++){
    unsigned short hh = bf16rn(th[o]);
    tH[o] = hh; tL[o] = bf16rn(th[o] - bf16tof(hh));
    unsigned short ph2 = bf16rn(ph[o]);
    pH[o] = ph2; pL[o] = bf16rn(ph[o] - bf16tof(ph2));
  }
  // row layout (16 ushorts): [H0-3 | L0-3 | H4-7 | L4-7]
  {
    u16x8* tp = (u16x8*)(thetaX + ((size_t)b*NPAD + n)*16);
    tp[0] = (u16x8){tH[0],tH[1],tH[2],tH[3], tL[0],tL[1],tL[2],tL[3]};
    tp[1] = (u16x8){tH[4],tH[5],tH[6],tH[7], tL[4],tL[5],tL[6],tL[7]};
    u16x8* pp = (u16x8*)(phiX + ((size_t)b*NPAD + n)*16);
    pp[0] = (u16x8){pH[0],pH[1],pH[2],pH[3], pL[0],pL[1],pL[2],pL[3]};
    pp[1] = (u16x8){pH[4],pH[5],pH[6],pH[7], pL[4],pL[5],pL[6],pL[7]};
  }
  #pragma unroll
  for (int o=0;o<8;o++)
    gT[((size_t)b*16 + o)*NPAD + n] = bf16rn(gg[o]);
  gT[((size_t)b*16 + 8)*NPAD + n] = 0x3F80;  // ones column -> l
}

// ---- K4a: partial MFMA flash attention over one key-half ----------------
// Verbatim r6 per-wave structure; block handles (b, qb, kh); local max.
__global__ __launch_bounds__(128) void k_attn_part(
    const unsigned short* __restrict__ thetaX, const unsigned short* __restrict__ phiX,
    const unsigned short* __restrict__ gT,
    float* __restrict__ mpart, float* __restrict__ Ypart){
  int blk = blockIdx.x;
  int b = blk / 82, rem = blk - b*82;
  int qb = rem >> 1, kh = rem & 1;
  int t = threadIdx.x, w = t >> 6, lane = t & 63;
  int h = lane >> 5, r31 = lane & 31;
  __shared__ float smm[2][32];
  __shared__ float sY[16][64];
  __shared__ float yl[32][12];

  const unsigned short* thx = thetaX + (size_t)b*NPAD*16;
  const unsigned short* phx = phiX   + (size_t)b*NPAD*16;

  // B-frags (theta for query q=r31): lane h supplies k=h*4+j
  s16x4 Bh, Bl;
  {
    u16x8 tv = *(const u16x8*)(thx + ((size_t)(qb*32 + r31))*16 + h*8);
    Bh = (s16x4){(short)tv[0],(short)tv[1],(short)tv[2],(short)tv[3]};
    Bl = (s16x4){(short)tv[4],(short)tv[5],(short)tv[6],(short)tv[7]};
  }

  int kbeg = kh ? 21 : 0;
  int kend = kh ? 41 : 21;
  int kmid = kh ? 31 : 11;
  int kt0 = w ? kmid : kbeg;
  int ktN = w ? kend : kmid;

  // ---- pass 1: approx scores (phi_hi * theta_hi), LOCAL half max --------
  float m = -1e30f;
  for (int kt = kt0; kt < ktN; ++kt){
    u16x8 av = *(const u16x8*)(phx + ((size_t)(kt*32 + r31))*16 + h*8);
    s16x4 Ah = (s16x4){(short)av[0],(short)av[1],(short)av[2],(short)av[3]};
    f32x16 S = __builtin_amdgcn_mfma_f32_32x32x8bf16_1k(Ah, Bh, (f32x16)(0.0f), 0, 0, 0);
    if (kt != 40){
      #pragma unroll
      for (int r=0;r<16;r++) m = fmaxf(m, S[r]);
    } else {
      #pragma unroll
      for (int r=0;r<8;r++) m = fmaxf(m, S[r]);
    }
  }
  m = fmaxf(m, __shfl_xor(m, 32));
  if (h == 0) smm[w][r31] = m;
  __syncthreads();
  m = fmaxf(smm[0][r31], smm[1][r31]);   // local (half) max for query r31
  if (w == 0 && h == 0)
    mpart[((size_t)((b*41 + qb)*2 + kh))*32 + r31] = m;

  // ---- pass 2: exact scores, exp2 with local m, PV via MFMA -------------
  f32x16 Y = (f32x16)(0.0f);
  int colc = (r31 < 9) ? r31 : 0;        // clamp V column (cols >8 unused)
  const unsigned short* gb2 = gT + ((size_t)b*16 + colc)*NPAD;

  for (int kt = kt0; kt < ktN; ++kt){
    u16x8 av = *(const u16x8*)(phx + ((size_t)(kt*32 + r31))*16 + h*8);
    s16x4 Ah = (s16x4){(short)av[0],(short)av[1],(short)av[2],(short)av[3]};
    s16x4 Al = (s16x4){(short)av[4],(short)av[5],(short)av[6],(short)av[7]};
    f32x16 S = __builtin_amdgcn_mfma_f32_32x32x8bf16_1k(Ah, Bl, (f32x16)(0.0f), 0, 0, 0);
    S = __builtin_amdgcn_mfma_f32_32x32x8bf16_1k(Al, Bh, S, 0, 0, 0);
    S = __builtin_amdgcn_mfma_f32_32x32x8bf16_1k(Ah, Bh, S, 0, 0, 0);
    if (kt == 40){
      #pragma unroll
      for (int r=8;r<16;r++) S[r] = -1e30f;   // mask pad keys 1296..1311
    }
    float p[16];
    #pragma unroll
    for (int r=0;r<16;r++) p[r] = __builtin_amdgcn_exp2f(S[r] - m);
    unsigned int c[8];
    #pragma unroll
    for (int i=0;i<8;i++){
      unsigned int cc;
      asm("v_cvt_pk_bf16_f32 %0, %1, %2" : "=v"(cc) : "v"(p[2*i]), "v"(p[2*i+1]));
      c[i] = cc;
    }
    #pragma unroll
    for (int mf=0; mf<4; ++mf){
      s16x4 Ap = __builtin_bit_cast(s16x4, (u32x2){c[2*mf], c[2*mf+1]});
      u32x2 vv = *(const u32x2*)(gb2 + kt*32 + mf*8 + h*4);
      s16x4 Vb = __builtin_bit_cast(s16x4, vv);
      Y = __builtin_amdgcn_mfma_f32_32x32x8bf16_1k(Ap, Vb, Y, 0, 0, 0);
    }
  }

  // ---- merge across the 2 waves, layout into yl -------------------------
  if (w == 1){
    #pragma unroll
    for (int r=0;r<16;r++) sY[r][lane] = Y[r];
  }
  __syncthreads();
  if (w == 0){
    #pragma unroll
    for (int r=0;r<16;r++) Y[r] += sY[r][lane];
    if (r31 < 9){
      #pragma unroll
      for (int r=0;r<16;r++){
        int q = (r&3) + 8*(r>>2) + 4*h;
        yl[q][r31] = Y[r];
      }
    }
  }
  __syncthreads();

  // ---- coalesced write-out of the 32x9 partial --------------------------
  float* yp = Ypart + (size_t)((b*41 + qb)*2 + kh)*288;
  for (int i = t; i < 288; i += 128){
    int q = i / 9, c2 = i - q*9;
    yp[i] = yl[q][c2];
  }
}

// ---- K4b: flash-merge two key-half partials + W-proj + residual ---------
__global__ __launch_bounds__(128) void k_attn_fin(
    const float* __restrict__ mpart, const float* __restrict__ Ypart,
    const float* __restrict__ corr, const float* __restrict__ sscale,
    const float* __restrict__ Ww, const float* __restrict__ Wb,
    float* __restrict__ out){
  int blk = blockIdx.x;
  int b = blk / 41, qb = blk - b*41;
  int t = threadIdx.x;
  __shared__ float yl[32][9];
  __shared__ float cf0[32], cf1[32];
  size_t p2 = (size_t)(b*41 + qb)*2;
  if (t < 32){
    float m0 = mpart[p2*32 + t];
    float m1 = mpart[(p2+1)*32 + t];
    float M = fmaxf(m0, m1);
    cf0[t] = __builtin_amdgcn_exp2f(m0 - M);
    cf1[t] = __builtin_amdgcn_exp2f(m1 - M);
  }
  __syncthreads();
  const float* y0 = Ypart + p2*288;
  const float* y1 = Ypart + (p2+1)*288;
  for (int i = t; i < 288; i += 128){
    int q = i / 9;
    ((float*)yl)[i] = y0[i]*cf0[q] + y1[i]*cf1[q];
  }
  __syncthreads();

  // epilogue: W-proj + residual; 128 threads = 32 q x 4 c-groups
  int q = t & 31, cg = t >> 5;
  int n = qb*32 + q;
  if (n < NHW){
    float il = 1.0f / yl[q][8];
    float yv[8];
    #pragma unroll
    for (int o=0;o<8;o++) yv[o] = yl[q][o] * il;
    const float* cp = corr + (size_t)b*NK*NHW + n;
    const float* ss = sscale + b*16;
    float* op = out + (size_t)b*NK*NHW + n;
    #pragma unroll
    for (int i=0;i<4;i++){
      int c2 = cg*4 + i;
      float z = Wb[c2];
      #pragma unroll
      for (int o=0;o<8;o++) z += Ww[c2*8+o]*yv[o];
      op[(size_t)c2*NHW] = z + cp[(size_t)c2*NHW]*ss[c2];
    }
  }
}

extern "C" void kernel_launch(void* const* d_in, const int* in_sizes, int n_in,
                              void* d_out, int out_size, void* d_ws, size_t ws_size,
                              hipStream_t stream){
  const float* feat1 = (const float*)d_in[0];
  const float* feat2 = (const float*)d_in[1];
  const float* bb1   = (const float*)d_in[2];
  const float* se_w1 = (const float*)d_in[3];
  const float* se_w2 = (const float*)d_in[4];
  const float* tw    = (const float*)d_in[5];
  const float* tb    = (const float*)d_in[6];
  const float* pw    = (const float*)d_in[7];
  const float* pb    = (const float*)d_in[8];
  const float* gw    = (const float*)d_in[9];
  const float* gb    = (const float*)d_in[10];
  const float* Ww    = (const float*)d_in[11];
  const float* Wb    = (const float*)d_in[12];
  float* out = (float*)d_out;

  float* ws = (float*)d_ws;
  float* kflat      = ws;                                // 64*256*16
  float* corr       = kflat + 64*256*16;                 // 64*16*1296
  float* partial_se = corr + (size_t)64*16*1296;         // 64*6*16
  float* sscale     = partial_se + 64*6*16;              // 64*16
  unsigned short* thetaX = (unsigned short*)(sscale + 64*16);   // 64*1312*16 u16
  unsigned short* phiX   = thetaX + (size_t)64*NPAD*16;         // 64*1312*16 u16
  unsigned short* gT     = phiX   + (size_t)64*NPAD*16;         // 64*16*1312 u16
  float* mpart = (float*)(gT + (size_t)64*16*NPAD);             // 64*41*2*32 f32
  float* Ypart = mpart + (size_t)64*41*2*32;                    // 64*41*2*288 f32

  hipLaunchKernelGGL(k_prpool, dim3(64*64), dim3(256), 0, stream, feat1, bb1, kflat);
  hipLaunchKernelGGL(k_corr, dim3(64*6), dim3(512), 0, stream, feat2, kflat, corr, partial_se);
  hipLaunchKernelGGL(k_tpg, dim3(64*21), dim3(64), 0, stream, corr, partial_se,
                     se_w1, se_w2, tw, tb, pw, pb, gw, gb, sscale, thetaX, phiX, gT);
  hipLaunchKernelGGL(k_attn_part, dim3(64*82), dim3(128), 0, stream,
                     thetaX, phiX, gT, mpart, Ypart);
  hipLaunchKernelGGL(k_attn_fin, dim3(64*41), dim3(128), 0, stream,
                     mpart, Ypart, corr, sscale, Ww, Wb, out);
}